// Round 11
// baseline (1258.557 us; speedup 1.0000x reference)
//
#include <hip/hip_runtime.h>
#include <stdint.h>
#include <stddef.h>

typedef __attribute__((ext_vector_type(8))) short bf16x8;
typedef __attribute__((ext_vector_type(4))) float f32x4;
typedef unsigned short u16;
typedef unsigned int u32;
typedef unsigned long long u64;

static constexpr int S_ = 2048, B_ = 2, H_ = 2048, NH_ = 16, D_ = 128, M_ = 2048, FF_ = 8192;
static constexpr int SB_ = S_ * B_;
static constexpr int MB_ = M_ * B_;

__device__ __forceinline__ float b2f(u16 b) {
  union { u32 u; float f; } v; v.u = ((u32)b) << 16; return v.f;
}
__device__ __forceinline__ u16 f2b(float f) {
  union { float f; u32 u; } v; v.f = f;
  u32 u = v.u;
  return (u16)((u + 0x7FFFu + ((u >> 16) & 1u)) >> 16);
}
__device__ __forceinline__ float geluf(float x) {
  float x3 = x * x * x;
  return 0.5f * x * (1.0f + tanhf(0.7978845608028654f * (x + 0.044715f * x3)));
}

#define LDSP(p) (reinterpret_cast<__attribute__((address_space(3))) uint32_t*>(reinterpret_cast<uintptr_t>(p)))
#define GLBP(p) (reinterpret_cast<const __attribute__((address_space(1))) uint32_t*>(reinterpret_cast<uintptr_t>(p)))

// ---------------------------------------------------------------- detectors
__global__ void detect_kinds(const u32* __restrict__ x0, const u32* __restrict__ mask, int* __restrict__ flags) {
  if (threadIdx.x == 0 && blockIdx.x == 0) {
    int cnt = 0;
    for (int i = 0; i < 256; ++i) {
      u32 e = (x0[i] >> 7) & 0xFFu;
      if (e >= 118u && e <= 130u) ++cnt;
    }
    flags[0] = (cnt >= 128) ? 0 : 1;
    int all01 = 1, allf = 1, allb = 1;
    for (int i = 0; i < 256; ++i) {
      u32 v = mask[i];
      if (v > 1u) all01 = 0;
      if (v != 0u && v != 0x3F800000u) allf = 0;
      u32 lo = v & 0xFFFFu, hi = v >> 16;
      if ((lo != 0u && lo != 0x3F80u) || (hi != 0u && hi != 0x3F80u)) allb = 0;
    }
    flags[1] = all01 ? 1 : (allf ? 3 : (allb ? 2 : 0));
  }
}

// mask -> packed bitmask: bit m = 1 iff UNMASKED
__global__ void mask_bits(const void* __restrict__ mraw, const int* __restrict__ flags, u64* __restrict__ bm) {
  int i = blockIdx.x * 256 + threadIdx.x;
  int kind = flags[1];
  int masked;
  if (kind == 1)      masked = ((const int*)mraw)[i] != 0;
  else if (kind == 3) masked = ((const float*)mraw)[i] != 0.0f;
  else if (kind == 2) masked = ((const u16*)mraw)[i] != 0;
  else                masked = ((const unsigned char*)mraw)[i] != 0;
  u64 vote = __ballot(masked == 0);
  if ((threadIdx.x & 63) == 0) bm[i >> 6] = vote;
}

// one launch for all 13 small f32 param conversions
__global__ void cvt_all(const void* s0, const void* s1, const void* s2, const void* s3,
                        const void* s4, const void* s5, const void* s6, const void* s7,
                        const void* s8, const void* s9, const void* s10, const void* s11,
                        const void* s12, const int* __restrict__ flags, float* __restrict__ SM) {
  const int i = blockIdx.x * 256 + threadIdx.x;
  if (i >= 40960) return;
  const void* src; int off;
  if (i < 8192)       { src = s0;  off = 0; }
  else if (i < 10240) { src = s1;  off = 8192; }
  else if (i < 12288) { src = s2;  off = 10240; }
  else if (i < 16384) { src = s3;  off = 12288; }
  else if (i < 18432) { src = s4;  off = 16384; }
  else if (i < 26624) { src = s5;  off = 18432; }
  else if (i < 28672) { src = s6;  off = 26624; }
  else if (i < 30720) { src = s7;  off = 28672; }
  else if (i < 32768) { src = s8;  off = 30720; }
  else if (i < 34816) { src = s9;  off = 32768; }
  else if (i < 36864) { src = s10; off = 34816; }
  else if (i < 38912) { src = s11; off = 36864; }
  else                { src = s12; off = 38912; }
  const int j = i - off;
  SM[i] = flags[0] ? ((const float*)src)[j] : b2f(((const u16*)src)[j]);
}

__global__ void cast_in_bf16(const void* __restrict__ src, const int* __restrict__ flags, u16* __restrict__ dst, int n8) {
  int i = blockIdx.x * 256 + threadIdx.x;
  if (i >= n8) return;
  if (flags[0]) {
    const float4* p = (const float4*)src;
    float4 a = p[i * 2], c = p[i * 2 + 1];
    bf16x8 o;
    o[0] = (short)f2b(a.x); o[1] = (short)f2b(a.y); o[2] = (short)f2b(a.z); o[3] = (short)f2b(a.w);
    o[4] = (short)f2b(c.x); o[5] = (short)f2b(c.y); o[6] = (short)f2b(c.z); o[7] = (short)f2b(c.w);
    *(bf16x8*)&dst[i * 8] = o;
  } else {
    *(bf16x8*)&dst[i * 8] = ((const bf16x8*)src)[i];
  }
}

// ------------------------------------------------------------ transpose+cast
__global__ __launch_bounds__(256) void transpose_cast(const void* __restrict__ in, const int* __restrict__ flags,
                                                      u16* __restrict__ out, int R, int C) {
  __shared__ u16 tile[64][65];
  const int isf = flags[0];
  const int tr = blockIdx.y * 64, tc = blockIdx.x * 64;
  const int tx = threadIdx.x & 63, ty = threadIdx.x >> 6;
  const float* inf = (const float*)in;
  const u16* inb = (const u16*)in;
#pragma unroll
  for (int i = 0; i < 16; ++i) {
    int r = ty * 16 + i;
    size_t idx = (size_t)(tr + r) * C + tc + tx;
    tile[r][tx] = isf ? f2b(inf[idx]) : inb[idx];
  }
  __syncthreads();
#pragma unroll
  for (int i = 0; i < 16; ++i) {
    int c = ty * 16 + i;
    out[(size_t)(tc + c) * R + tr + tx] = tile[tx][c];
  }
}

// ---------------------------------------------------------------- layernorm
template <int EXT>
__global__ __launch_bounds__(256) void layernorm_k(const void* __restrict__ xin, const int* __restrict__ flags,
                                                   const float* __restrict__ g, const float* __restrict__ bta,
                                                   u16* __restrict__ out) {
  const int row = blockIdx.x, t = threadIdx.x;
  float v[8];
  bool bfmode = EXT && (flags[0] == 0);
  if (bfmode) {
    const u16* xr = (const u16*)xin + (size_t)row * H_ + t * 8;
    bf16x8 a = *(const bf16x8*)xr;
#pragma unroll
    for (int j = 0; j < 8; ++j) v[j] = b2f((u16)a[j]);
  } else {
    const float* xr = (const float*)xin + (size_t)row * H_ + t * 8;
    float4 a = *(const float4*)xr, c = *(const float4*)(xr + 4);
    v[0] = a.x; v[1] = a.y; v[2] = a.z; v[3] = a.w;
    v[4] = c.x; v[5] = c.y; v[6] = c.z; v[7] = c.w;
  }
  float s1 = 0.f, s2 = 0.f;
#pragma unroll
  for (int j = 0; j < 8; ++j) { s1 += v[j]; s2 += v[j] * v[j]; }
#pragma unroll
  for (int off = 32; off > 0; off >>= 1) { s1 += __shfl_down(s1, off); s2 += __shfl_down(s2, off); }
  __shared__ float red[8];
  const int w = t >> 6;
  if ((t & 63) == 0) { red[w] = s1; red[4 + w] = s2; }
  __syncthreads();
  s1 = red[0] + red[1] + red[2] + red[3];
  s2 = red[4] + red[5] + red[6] + red[7];
  const float mean = s1 * (1.0f / H_);
  const float rstd = rsqrtf(s2 * (1.0f / H_) - mean * mean + 1e-5f);
  bf16x8 o;
#pragma unroll
  for (int j = 0; j < 8; ++j) {
    float y = (v[j] - mean) * rstd * g[t * 8 + j] + bta[t * 8 + j];
    o[j] = (short)f2b(y);
  }
  *(bf16x8*)(out + (size_t)row * H_ + t * 8) = o;
}

// ------------------------------------------------------------------- GEMM
// 4-slot fully-counted pipeline.  128x128 tile, 256 thr = 4 waves (2Mx2N,
// per-wave 64x64).  BK=32, 4-slot ring (64KB LDS -> 2 blocks/CU).
// Per slice: {STG(s+3) [4 gload_lds]; RD(s+1) [8 ds_read_b128 read-ahead];
// 16 MFMA (tile s, frags read last slice); vmcnt(4); barrier}.
// NO manual lgkm fences: compiler emits counted lgkmcnt(8) before each MFMA
// cluster (RD(s+1) stays outstanding).  vmcnt(4) keeps STG(s+3) in flight
// and forces STG(s+2) (needed by next slice's RD) -> 2-slice latency cover,
// never drains mid-loop.  Hazards (all verified):
//   RAW: RD(s+1) needs STG(s+1): forced at prev fence's vmcnt(4).
//   WAR: STG(s+3) hits slot of tile s-1; its reads drained by compiler wait
//        before MM(s-1), one barrier earlier.
// LDS layout (per operand, per slot): 64 super-rows x 128B (2 K-rows packed),
// slot-swizzle sp_stored = (((row&1)<<2)|chunk) ^ ((row>>1)&7) -> ds_read
// 2-way bank alias (free, m136); linear gload_lds dest + inverse-permuted
// global source (rule #21).  Measured conflict-free in r5.
template <int GELU, int RES, int WF, int WB, int ODYN>
__global__ __launch_bounds__(256, 2) void gemmra(const u16* __restrict__ A, const u16* __restrict__ Bt,
                                                 const float* __restrict__ bias, const float* __restrict__ res,
                                                 void* __restrict__ outF, u16* __restrict__ outB,
                                                 const int* __restrict__ flags, int Mr, int N, int K) {
  __shared__ u16 lds[32768];   // 64 KiB: 4 slots x (A 4096 u16 + B 4096 u16)
  const int t = threadIdx.x;
  const int w = t >> 6, l = t & 63, lr = l & 15, lk = l >> 4;
  const int wr = w >> 1, wc = w & 1;
  // 2D XCD-chunked block mapping
  const int gx = gridDim.x, gy = gridDim.y;
  const int orig = blockIdx.y * gx + blockIdx.x;
  const int nwg = gx * gy, per = nwg >> 3;
  int tm, tn;
  if ((gx & 7) == 0 && (per & 7) == 0) {
    const int xcd = orig & 7, p = orig >> 3;
    const int ncx = gx >> 3, cy = per >> 3;
    const int ccol = xcd % ncx, crow = xcd / ncx;
    const int px = p & 7, py = p >> 3;
    tn = (ccol * 8 + px) * 128;
    tm = (crow * cy + py) * 128;
  } else {
    tn = (orig % gx) * 128;
    tm = (orig / gx) * 128;
  }
  // staging source offsets (inverse-swizzled), 2 rounds per operand per slice
  u32 aofs[2], bofs[2];
#pragma unroll
  for (int i = 0; i < 2; ++i) {
    const int idx = i * 256 + t;          // chunk index 0..511
    const int sr = idx >> 3, sp = idx & 7;
    const int spp = sp ^ (sr & 7);
    const int row = (sr << 1) | (spp >> 2);
    const int ck = spp & 3;
    aofs[i] = (u32)(tm + row) * (u32)K + (u32)ck * 8;
    bofs[i] = (u32)(tn + row) * (u32)K + (u32)ck * 8;
  }
  const int wdst = w * 512;               // u16: wave chunk in a 2048-u16 round
  // ds_read offsets (u16, region-relative): R = base + f*16 + lr, chunk lk
  int offA[4], offB[4];
#pragma unroll
  for (int f = 0; f < 4; ++f) {
    const int Ra = wr * 64 + f * 16 + lr;
    const int sra = Ra >> 1;
    offA[f] = sra * 64 + (((((Ra & 1) << 2) | lk) ^ (sra & 7)) << 3);
    const int Rb = wc * 64 + f * 16 + lr;
    const int srb = Rb >> 1;
    offB[f] = srb * 64 + (((((Rb & 1) << 2) | lk) ^ (srb & 7)) << 3);
  }

  const int NS = K >> 5;   // BK=32 slices (even for all our K)
  f32x4 acc[4][4] = {};

#define STG(sl) do {                                                                                  \
    u16* Ad = lds + ((sl) & 3) * 8192;                                                                \
    u16* Bd = Ad + 4096;                                                                              \
    const u32 ko = (u32)(sl) * 32;                                                                    \
    _Pragma("unroll")                                                                                 \
    for (int i = 0; i < 2; ++i) {                                                                     \
      __builtin_amdgcn_global_load_lds(GLBP(A + aofs[i] + ko), LDSP(Ad + i * 2048 + wdst), 16, 0, 0); \
      __builtin_amdgcn_global_load_lds(GLBP(Bt + bofs[i] + ko), LDSP(Bd + i * 2048 + wdst), 16, 0, 0);\
    }                                                                                                 \
  } while (0)
#define RD(afX, bqX, sl) do {                                                                         \
    const u16* As_ = lds + ((sl) & 3) * 8192;                                                         \
    const u16* Bs_ = As_ + 4096;                                                                      \
    _Pragma("unroll")                                                                                 \
    for (int f = 0; f < 4; ++f) {                                                                     \
      afX[f] = *(const bf16x8*)(As_ + offA[f]);                                                       \
      bqX[f] = *(const bf16x8*)(Bs_ + offB[f]);                                                       \
    }                                                                                                 \
  } while (0)
#define MM(afX, bqX)                                                                                  \
  __builtin_amdgcn_s_setprio(1);                                                                      \
  _Pragma("unroll") for (int nf = 0; nf < 4; ++nf)                                                    \
  _Pragma("unroll") for (int mf = 0; mf < 4; ++mf)                                                    \
    acc[mf][nf] = __builtin_amdgcn_mfma_f32_16x16x32_bf16(afX[mf], bqX[nf], acc[mf][nf], 0, 0, 0);    \
  __builtin_amdgcn_s_setprio(0);

  bf16x8 fAa[4], fAb[4], fBa[4], fBb[4];

  // prologue: stage slots 0..2; force slots 0,1 landed (keep 2 in flight)
  STG(0); STG(1); STG(2);
  asm volatile("s_waitcnt vmcnt(4)" ::: "memory");
  __builtin_amdgcn_s_barrier();
  RD(fAa, fAb, 0);

  for (int s = 0; s < NS; s += 2) {
    // ---- slice s (even): consume fA (tile s)
    if (s + 3 < NS) STG(s + 3);
    RD(fBa, fBb, s + 1);
    MM(fAa, fAb);
    if (s + 3 < NS) { asm volatile("s_waitcnt vmcnt(4)" ::: "memory"); }
    else            { asm volatile("s_waitcnt vmcnt(0)" ::: "memory"); }
    __builtin_amdgcn_s_barrier();
    // ---- slice s+1 (odd): consume fB (tile s+1)
    if (s + 4 < NS) STG(s + 4);
    if (s + 2 < NS) RD(fAa, fAb, s + 2);
    MM(fBa, fBb);
    if (s + 2 < NS) {
      if (s + 4 < NS) { asm volatile("s_waitcnt vmcnt(4)" ::: "memory"); }
      else            { asm volatile("s_waitcnt vmcnt(0)" ::: "memory"); }
      __builtin_amdgcn_s_barrier();
    }
  }
#undef STG
#undef RD
#undef MM

  const int obf = ODYN ? (flags[0] ? 0 : 1) : 0;
  (void)Mr;
#pragma unroll
  for (int mf = 0; mf < 4; ++mf) {
#pragma unroll
    for (int nf = 0; nf < 4; ++nf) {
      const int col = tn + wc * 64 + nf * 16 + lr;
      const float bv = bias[col];
#pragma unroll
      for (int j = 0; j < 4; ++j) {
        const int rw = tm + wr * 64 + mf * 16 + lk * 4 + j;
        float vv = acc[mf][nf][j] + bv;
        if (RES) vv += res[(size_t)rw * N + col];
        if (GELU) vv = geluf(vv);
        if (WF) {
          if (ODYN && obf) ((u16*)outF)[(size_t)rw * N + col] = f2b(vv);
          else ((float*)outF)[(size_t)rw * N + col] = vv;
        }
        if (WB) outB[(size_t)rw * N + col] = f2b(vv);
      }
    }
  }
}

// --------------------------------------------------------------- l2 norms
__global__ __launch_bounds__(256) void l2_q(const float* __restrict__ qpre, u16* __restrict__ Q) {
  const int t = threadIdx.x;
  const int g = blockIdx.x * 64 + (t >> 2);
  const int lg = t & 3;
  const int h = g & (NH_ - 1), sb = g >> 4;
  const float* p = qpre + (size_t)sb * H_ + h * D_ + lg * 32;
  float vv[32];
  float ss = 0.f;
#pragma unroll
  for (int i = 0; i < 8; ++i) {
    float4 a = *(const float4*)&p[i * 4];
    vv[i * 4 + 0] = a.x; vv[i * 4 + 1] = a.y; vv[i * 4 + 2] = a.z; vv[i * 4 + 3] = a.w;
    ss += a.x * a.x + a.y * a.y + a.z * a.z + a.w * a.w;
  }
  ss += __shfl_xor(ss, 1); ss += __shfl_xor(ss, 2);
  const float sc = rsqrtf(ss + 1e-12f);
  const int s = sb >> 1, b = sb & 1;
  u16* o = Q + ((size_t)(b * NH_ + h) * S_ + s) * D_ + lg * 32;
#pragma unroll
  for (int i = 0; i < 4; ++i) {
    bf16x8 ov;
#pragma unroll
    for (int j = 0; j < 8; ++j) ov[j] = (short)f2b(vv[i * 8 + j] * sc);
    *(bf16x8*)&o[i * 8] = ov;
  }
}

__global__ __launch_bounds__(256) void l2_kv(const float* __restrict__ kvpre, u16* __restrict__ Kq, u16* __restrict__ Vt) {
  __shared__ u16 vtT[128][72];
  const int t = threadIdx.x;
  const int bid = blockIdx.x;
  const int mt = bid & 31, h = (bid >> 5) & 15, b = bid >> 9;
  const int lm = t >> 2, lg = t & 3;
  const int m = mt * 64 + lm;
  const size_t rowoff = (size_t)(m * B_ + b) * (2 * H_) + h * 256;
  float vv[32];
  { // K half
    const float* p = kvpre + rowoff + lg * 32;
    float ss = 0.f;
#pragma unroll
    for (int i = 0; i < 8; ++i) {
      float4 a = *(const float4*)&p[i * 4];
      vv[i * 4 + 0] = a.x; vv[i * 4 + 1] = a.y; vv[i * 4 + 2] = a.z; vv[i * 4 + 3] = a.w;
      ss += a.x * a.x + a.y * a.y + a.z * a.z + a.w * a.w;
    }
    ss += __shfl_xor(ss, 1); ss += __shfl_xor(ss, 2);
    const float sc = rsqrtf(ss + 1e-12f);
    u16* o = Kq + ((size_t)(b * NH_ + h) * M_ + m) * D_ + lg * 32;
#pragma unroll
    for (int i = 0; i < 4; ++i) {
      bf16x8 ov;
#pragma unroll
      for (int j = 0; j < 8; ++j) ov[j] = (short)f2b(vv[i * 8 + j] * sc);
      *(bf16x8*)&o[i * 8] = ov;
    }
  }
  { // V half -> LDS transposed
    const float* p = kvpre + rowoff + 128 + lg * 32;
    float ss = 0.f;
#pragma unroll
    for (int i = 0; i < 8; ++i) {
      float4 a = *(const float4*)&p[i * 4];
      vv[i * 4 + 0] = a.x; vv[i * 4 + 1] = a.y; vv[i * 4 + 2] = a.z; vv[i * 4 + 3] = a.w;
      ss += a.x * a.x + a.y * a.y + a.z * a.z + a.w * a.w;
    }
    ss += __shfl_xor(ss, 1); ss += __shfl_xor(ss, 2);
    const float sc = rsqrtf(ss + 1e-12f);
#pragma unroll
    for (int i = 0; i < 32; ++i) vtT[lg * 32 + i][lm] = f2b(vv[i] * sc);
  }
  __syncthreads();
  const int d = t >> 1, half = t & 1;
  u16* o = Vt + ((size_t)(b * NH_ + h) * D_ + d) * M_ + mt * 64 + half * 32;
#pragma unroll
  for (int i = 0; i < 4; ++i) {
    bf16x8 ov = *(const bf16x8*)&vtT[d][half * 32 + i * 8];
    *(bf16x8*)&o[i * 8] = ov;
  }
}

// -------------------------------------------------------------- attention
// unchanged from round 8 (verified; ~130 us)
__global__ __launch_bounds__(256, 3) void attn_k(const u16* __restrict__ Q, const u16* __restrict__ Kq,
                                                 const u16* __restrict__ Vt, const u32* __restrict__ BM32,
                                                 u16* __restrict__ ctx) {
  __shared__ u16 Kl[2][4096];
  __shared__ u16 Vl[2][4096];
  __shared__ u16 Pl[4][16 * 40];
  const int t = threadIdx.x, w = t >> 6, l = t & 63, lr = l & 15, lk = l >> 4;
  const int lin = blockIdx.x;
  const int xcd = lin & 7, idx = lin >> 3;
  const int bh = xcd * 4 + (idx >> 5);
  const int chunk = idx & 31;
  const int b = bh >> 4, h = bh & 15;
  const int srow = chunk * 64 + w * 16;
  const u16* Qb = Q + ((size_t)bh * S_ + srow) * D_;
  bf16x8 qf[4];
#pragma unroll
  for (int kc = 0; kc < 4; ++kc)
    qf[kc] = *(const bf16x8*)&Qb[lr * D_ + kc * 32 + lk * 8];
  f32x4 oacc[8] = {};
  float den[4] = {};
  const u16* Kb = Kq + (size_t)bh * M_ * D_;
  const u16* Vb = Vt + (size_t)bh * D_ * M_;
  const float invn = 0.08838834764831845f;
  u32 ksrc[2], vsrc[2];
#pragma unroll
  for (int i = 0; i < 2; ++i) {
    const int kidx = i * 256 + t;
    const int kr = kidx >> 4, kc_ = (kidx & 15) ^ (kr & 7);
    ksrc[i] = (u32)kr * D_ + (u32)kc_ * 8;
    const int vidx = i * 256 + t;
    const int vd = vidx >> 2, vc = (vidx & 3) ^ ((vd >> 1) & 3);
    vsrc[i] = (u32)vd * M_ + (u32)vc * 8;
  }
  const int wdst = w * 64 * 8;
  u32 mrow[4];
#pragma unroll
  for (int j2 = 0; j2 < 4; ++j2)
    mrow[j2] = ((u32)b * S_ + (u32)(srow + lk * 4 + j2)) * 64u;

#define STG(buf, m0) do {                                                                              \
    _Pragma("unroll")                                                                                  \
    for (int i = 0; i < 2; ++i) {                                                                      \
      __builtin_amdgcn_global_load_lds(GLBP(Kb + (size_t)(m0) * D_ + ksrc[i]),                         \
                                       LDSP(&Kl[buf][i * 2048 + wdst]), 16, 0, 0);                     \
      __builtin_amdgcn_global_load_lds(GLBP(Vb + (size_t)(m0) + vsrc[i]),                              \
                                       LDSP(&Vl[buf][i * 2048 + wdst]), 16, 0, 0);                     \
    }                                                                                                  \
  } while (0)

  STG(0, 0);
  asm volatile("s_waitcnt vmcnt(0)" ::: "memory");
  __builtin_amdgcn_s_barrier();
  int cur = 0;

  for (int t64 = 0; t64 < M_ / 32; ++t64) {
    const int m0 = t64 * 32;
    if (t64 + 1 < M_ / 32) STG(cur ^ 1, m0 + 32);
    u32 mw[4];
#pragma unroll
    for (int j2 = 0; j2 < 4; ++j2) mw[j2] = BM32[mrow[j2] + t64];
    f32x4 sc[2] = {};
#pragma unroll
    for (int mf = 0; mf < 2; ++mf) {
      const int r = mf * 16 + lr;
#pragma unroll
      for (int kc = 0; kc < 4; ++kc) {
        const int cc = ((kc * 4 + lk) ^ (r & 7));
        bf16x8 kfv = *(const bf16x8*)&Kl[cur][r * 128 + cc * 8];
        sc[mf] = __builtin_amdgcn_mfma_f32_16x16x32_bf16(qf[kc], kfv, sc[mf], 0, 0, 0);
      }
    }
#pragma unroll
    for (int j2 = 0; j2 < 4; ++j2) {
      const int rloc = lk * 4 + j2;
#pragma unroll
      for (int mf = 0; mf < 2; ++mf) {
        float p = __expf(sc[mf][j2] * invn);
        p = ((mw[j2] >> (mf * 16 + lr)) & 1u) ? p : 0.0f;
        den[j2] += p;
        Pl[w][rloc * 40 + mf * 16 + lr] = f2b(p);
      }
    }
    asm volatile("s_waitcnt lgkmcnt(0)" ::: "memory");
    __builtin_amdgcn_sched_barrier(0);
    bf16x8 pa = *(const bf16x8*)&Pl[w][lr * 40 + lk * 8];
#pragma unroll
    for (int nf = 0; nf < 8; ++nf) {
      const int d = nf * 16 + lr;
      const int cc = lk ^ ((d >> 1) & 3);
      bf16x8 vfv = *(const bf16x8*)&Vl[cur][d * 32 + cc * 8];
      oacc[nf] = __builtin_amdgcn_mfma_f32_16x16x32_bf16(pa, vfv, oacc[nf], 0, 0, 0);
    }
    asm volatile("s_waitcnt vmcnt(0)" ::: "memory");
    __builtin_amdgcn_s_barrier();
    cur ^= 1;
  }
#undef STG
#pragma unroll
  for (int j2 = 0; j2 < 4; ++j2) {
    float d = den[j2];
    d += __shfl_xor(d, 1); d += __shfl_xor(d, 2); d += __shfl_xor(d, 4); d += __shfl_xor(d, 8);
    den[j2] = 1.0f / fmaxf(d, 1e-20f);
  }
#pragma unroll
  for (int nf = 0; nf < 8; ++nf)
#pragma unroll
    for (int j2 = 0; j2 < 4; ++j2) {
      const int s = srow + lk * 4 + j2;
      const int dd = nf * 16 + lr;
      ctx[((size_t)s * B_ + b) * H_ + h * D_ + dd] = f2b(oacc[nf][j2] * den[j2]);
    }
}

// ------------------------------------------------------------------- host
extern "C" void kernel_launch(void* const* d_in, const int* in_sizes, int n_in,
                              void* d_out, int out_size, void* d_ws, size_t ws_size,
                              hipStream_t stream) {
  (void)in_sizes; (void)n_in; (void)out_size; (void)ws_size;
  char* ws = (char*)d_ws;
  u16* WT     = (u16*)(ws + 0);
  void* MID   = (void*)(ws + 33554432);
  float* XF   = (float*)(ws + 100663296);
  u16* HB     = (u16*)(ws + 134217728);
  u16* MEMB   = (u16*)(ws + 150994944);
  u16* QB     = (u16*)(ws + 167772160);
  u16* KB     = (u16*)(ws + 184549376);
  u16* VTB    = (u16*)(ws + 201326592);
  u64* BMB    = (u64*)(ws + 218103808);
  float* SM   = (float*)(ws + 234881024);
  int* FLAGS  = (int*)(ws + 235044864);

  float* Bias1  = SM + 0;
  float* Bias1o = SM + 8192;
  float* BiasQ  = SM + 10240;
  float* BiasKV = SM + 12288;
  float* BiasD  = SM + 16384;
  float* Bias2  = SM + 18432;
  float* Bias2o = SM + 26624;
  float* G1v = SM + 28672; float* B1v = SM + 30720;
  float* G2v = SM + 32768; float* B2v = SM + 34816;
  float* G3v = SM + 36864; float* B3v = SM + 38912;

  detect_kinds<<<1, 64, 0, stream>>>((const u32*)d_in[0], (const u32*)d_in[2], FLAGS);

  cvt_all<<<160, 256, 0, stream>>>(d_in[10], d_in[12], d_in[14], d_in[16], d_in[18],
                                   d_in[20], d_in[22], d_in[3], d_in[4], d_in[5],
                                   d_in[6], d_in[7], d_in[8], FLAGS, SM);

  mask_bits<<<(B_ * S_ * M_) / 256, 256, 0, stream>>>(d_in[2], FLAGS, BMB);
  cast_in_bf16<<<(MB_ * H_ / 8) / 256, 256, 0, stream>>>(d_in[1], FLAGS, MEMB, MB_ * H_ / 8);

  dim3 blk(256);
  // ---- mlp1
  layernorm_k<1><<<SB_, blk, 0, stream>>>(d_in[0], FLAGS, G1v, B1v, HB);
  transpose_cast<<<dim3(FF_ / 64, H_ / 64), blk, 0, stream>>>(d_in[9], FLAGS, WT, H_, FF_);
  gemmra<1, 0, 0, 1, 0><<<dim3(FF_ / 128, SB_ / 128), blk, 0, stream>>>(HB, WT, Bias1, nullptr, nullptr, (u16*)MID, FLAGS, SB_, FF_, H_);
  transpose_cast<<<dim3(H_ / 64, FF_ / 64), blk, 0, stream>>>(d_in[11], FLAGS, WT, FF_, H_);
  gemmra<0, 0, 1, 0, 0><<<dim3(H_ / 128, SB_ / 128), blk, 0, stream>>>((u16*)MID, WT, Bias1o, nullptr, XF, nullptr, FLAGS, SB_, H_, FF_);

  // ---- memory attention
  layernorm_k<0><<<SB_, blk, 0, stream>>>(XF, FLAGS, G2v, B2v, HB);
  transpose_cast<<<dim3(H_ / 64, H_ / 64), blk, 0, stream>>>(d_in[13], FLAGS, WT, H_, H_);
  gemmra<0, 0, 1, 0, 0><<<dim3(H_ / 128, SB_ / 128), blk, 0, stream>>>(HB, WT, BiasQ, nullptr, MID, nullptr, FLAGS, SB_, H_, H_);
  l2_q<<<(SB_ * NH_) / 64, blk, 0, stream>>>((const float*)MID, QB);
  transpose_cast<<<dim3(2 * H_ / 64, H_ / 64), blk, 0, stream>>>(d_in[15], FLAGS, WT, H_, 2 * H_);
  gemmra<0, 0, 1, 0, 0><<<dim3(2 * H_ / 128, MB_ / 128), blk, 0, stream>>>(MEMB, WT, BiasKV, nullptr, MID, nullptr, FLAGS, MB_, 2 * H_, H_);
  l2_kv<<<B_ * NH_ * (M_ / 64), blk, 0, stream>>>((const float*)MID, KB, VTB);
  attn_k<<<1024, blk, 0, stream>>>(QB, KB, VTB, (const u32*)BMB, MEMB);
  transpose_cast<<<dim3(H_ / 64, H_ / 64), blk, 0, stream>>>(d_in[17], FLAGS, WT, H_, H_);
  gemmra<0, 1, 1, 0, 0><<<dim3(H_ / 128, SB_ / 128), blk, 0, stream>>>(MEMB, WT, BiasD, XF, XF, nullptr, FLAGS, SB_, H_, H_);

  // ---- mlp2
  layernorm_k<0><<<SB_, blk, 0, stream>>>(XF, FLAGS, G3v, B3v, HB);
  transpose_cast<<<dim3(FF_ / 64, H_ / 64), blk, 0, stream>>>(d_in[19], FLAGS, WT, H_, FF_);
  gemmra<1, 0, 0, 1, 0><<<dim3(FF_ / 128, SB_ / 128), blk, 0, stream>>>(HB, WT, Bias2, nullptr, nullptr, (u16*)MID, FLAGS, SB_, FF_, H_);
  transpose_cast<<<dim3(H_ / 64, FF_ / 64), blk, 0, stream>>>(d_in[21], FLAGS, WT, FF_, H_);
  gemmra<0, 1, 1, 0, 1><<<dim3(H_ / 128, SB_ / 128), blk, 0, stream>>>((u16*)MID, WT, Bias2o, XF, d_out, nullptr, FLAGS, SB_, H_, FF_);
}

// Round 12
// 1173.259 us; speedup vs baseline: 1.0727x; 1.0727x over previous
//
#include <hip/hip_runtime.h>
#include <stdint.h>
#include <stddef.h>

typedef __attribute__((ext_vector_type(8))) short bf16x8;
typedef __attribute__((ext_vector_type(4))) float f32x4;
typedef __attribute__((ext_vector_type(16))) float f32x16;
typedef unsigned short u16;
typedef unsigned int u32;
typedef unsigned long long u64;

static constexpr int S_ = 2048, B_ = 2, H_ = 2048, NH_ = 16, D_ = 128, M_ = 2048, FF_ = 8192;
static constexpr int SB_ = S_ * B_;
static constexpr int MB_ = M_ * B_;

__device__ __forceinline__ float b2f(u16 b) {
  union { u32 u; float f; } v; v.u = ((u32)b) << 16; return v.f;
}
__device__ __forceinline__ u16 f2b(float f) {
  union { float f; u32 u; } v; v.f = f;
  u32 u = v.u;
  return (u16)((u + 0x7FFFu + ((u >> 16) & 1u)) >> 16);
}
__device__ __forceinline__ float geluf(float x) {
  float x3 = x * x * x;
  return 0.5f * x * (1.0f + tanhf(0.7978845608028654f * (x + 0.044715f * x3)));
}

#define LDSP(p) (reinterpret_cast<__attribute__((address_space(3))) uint32_t*>(reinterpret_cast<uintptr_t>(p)))
#define GLBP(p) (reinterpret_cast<const __attribute__((address_space(1))) uint32_t*>(reinterpret_cast<uintptr_t>(p)))

// ---------------------------------------------------------------- detectors
__global__ void detect_kinds(const u32* __restrict__ x0, const u32* __restrict__ mask, int* __restrict__ flags) {
  if (threadIdx.x == 0 && blockIdx.x == 0) {
    int cnt = 0;
    for (int i = 0; i < 256; ++i) {
      u32 e = (x0[i] >> 7) & 0xFFu;
      if (e >= 118u && e <= 130u) ++cnt;
    }
    flags[0] = (cnt >= 128) ? 0 : 1;
    int all01 = 1, allf = 1, allb = 1;
    for (int i = 0; i < 256; ++i) {
      u32 v = mask[i];
      if (v > 1u) all01 = 0;
      if (v != 0u && v != 0x3F800000u) allf = 0;
      u32 lo = v & 0xFFFFu, hi = v >> 16;
      if ((lo != 0u && lo != 0x3F80u) || (hi != 0u && hi != 0x3F80u)) allb = 0;
    }
    flags[1] = all01 ? 1 : (allf ? 3 : (allb ? 2 : 0));
  }
}

// mask -> packed bitmask: bit m = 1 iff UNMASKED
__global__ void mask_bits(const void* __restrict__ mraw, const int* __restrict__ flags, u64* __restrict__ bm) {
  int i = blockIdx.x * 256 + threadIdx.x;
  int kind = flags[1];
  int masked;
  if (kind == 1)      masked = ((const int*)mraw)[i] != 0;
  else if (kind == 3) masked = ((const float*)mraw)[i] != 0.0f;
  else if (kind == 2) masked = ((const u16*)mraw)[i] != 0;
  else                masked = ((const unsigned char*)mraw)[i] != 0;
  u64 vote = __ballot(masked == 0);
  if ((threadIdx.x & 63) == 0) bm[i >> 6] = vote;
}

// one launch for all 13 small f32 param conversions
__global__ void cvt_all(const void* s0, const void* s1, const void* s2, const void* s3,
                        const void* s4, const void* s5, const void* s6, const void* s7,
                        const void* s8, const void* s9, const void* s10, const void* s11,
                        const void* s12, const int* __restrict__ flags, float* __restrict__ SM) {
  const int i = blockIdx.x * 256 + threadIdx.x;
  if (i >= 40960) return;
  const void* src; int off;
  if (i < 8192)       { src = s0;  off = 0; }
  else if (i < 10240) { src = s1;  off = 8192; }
  else if (i < 12288) { src = s2;  off = 10240; }
  else if (i < 16384) { src = s3;  off = 12288; }
  else if (i < 18432) { src = s4;  off = 16384; }
  else if (i < 26624) { src = s5;  off = 18432; }
  else if (i < 28672) { src = s6;  off = 26624; }
  else if (i < 30720) { src = s7;  off = 28672; }
  else if (i < 32768) { src = s8;  off = 30720; }
  else if (i < 34816) { src = s9;  off = 32768; }
  else if (i < 36864) { src = s10; off = 34816; }
  else if (i < 38912) { src = s11; off = 36864; }
  else                { src = s12; off = 38912; }
  const int j = i - off;
  SM[i] = flags[0] ? ((const float*)src)[j] : b2f(((const u16*)src)[j]);
}

__global__ void cast_in_bf16(const void* __restrict__ src, const int* __restrict__ flags, u16* __restrict__ dst, int n8) {
  int i = blockIdx.x * 256 + threadIdx.x;
  if (i >= n8) return;
  if (flags[0]) {
    const float4* p = (const float4*)src;
    float4 a = p[i * 2], c = p[i * 2 + 1];
    bf16x8 o;
    o[0] = (short)f2b(a.x); o[1] = (short)f2b(a.y); o[2] = (short)f2b(a.z); o[3] = (short)f2b(a.w);
    o[4] = (short)f2b(c.x); o[5] = (short)f2b(c.y); o[6] = (short)f2b(c.z); o[7] = (short)f2b(c.w);
    *(bf16x8*)&dst[i * 8] = o;
  } else {
    *(bf16x8*)&dst[i * 8] = ((const bf16x8*)src)[i];
  }
}

// ------------------------------------------------------------ transpose+cast
__global__ __launch_bounds__(256) void transpose_cast(const void* __restrict__ in, const int* __restrict__ flags,
                                                      u16* __restrict__ out, int R, int C) {
  __shared__ u16 tile[64][65];
  const int isf = flags[0];
  const int tr = blockIdx.y * 64, tc = blockIdx.x * 64;
  const int tx = threadIdx.x & 63, ty = threadIdx.x >> 6;
  const float* inf = (const float*)in;
  const u16* inb = (const u16*)in;
#pragma unroll
  for (int i = 0; i < 16; ++i) {
    int r = ty * 16 + i;
    size_t idx = (size_t)(tr + r) * C + tc + tx;
    tile[r][tx] = isf ? f2b(inf[idx]) : inb[idx];
  }
  __syncthreads();
#pragma unroll
  for (int i = 0; i < 16; ++i) {
    int c = ty * 16 + i;
    out[(size_t)(tc + c) * R + tr + tx] = tile[tx][c];
  }
}

// ---------------------------------------------------------------- layernorm
template <int EXT>
__global__ __launch_bounds__(256) void layernorm_k(const void* __restrict__ xin, const int* __restrict__ flags,
                                                   const float* __restrict__ g, const float* __restrict__ bta,
                                                   u16* __restrict__ out) {
  const int row = blockIdx.x, t = threadIdx.x;
  float v[8];
  bool bfmode = EXT && (flags[0] == 0);
  if (bfmode) {
    const u16* xr = (const u16*)xin + (size_t)row * H_ + t * 8;
    bf16x8 a = *(const bf16x8*)xr;
#pragma unroll
    for (int j = 0; j < 8; ++j) v[j] = b2f((u16)a[j]);
  } else {
    const float* xr = (const float*)xin + (size_t)row * H_ + t * 8;
    float4 a = *(const float4*)xr, c = *(const float4*)(xr + 4);
    v[0] = a.x; v[1] = a.y; v[2] = a.z; v[3] = a.w;
    v[4] = c.x; v[5] = c.y; v[6] = c.z; v[7] = c.w;
  }
  float s1 = 0.f, s2 = 0.f;
#pragma unroll
  for (int j = 0; j < 8; ++j) { s1 += v[j]; s2 += v[j] * v[j]; }
#pragma unroll
  for (int off = 32; off > 0; off >>= 1) { s1 += __shfl_down(s1, off); s2 += __shfl_down(s2, off); }
  __shared__ float red[8];
  const int w = t >> 6;
  if ((t & 63) == 0) { red[w] = s1; red[4 + w] = s2; }
  __syncthreads();
  s1 = red[0] + red[1] + red[2] + red[3];
  s2 = red[4] + red[5] + red[6] + red[7];
  const float mean = s1 * (1.0f / H_);
  const float rstd = rsqrtf(s2 * (1.0f / H_) - mean * mean + 1e-5f);
  bf16x8 o;
#pragma unroll
  for (int j = 0; j < 8; ++j) {
    float y = (v[j] - mean) * rstd * g[t * 8 + j] + bta[t * 8 + j];
    o[j] = (short)f2b(y);
  }
  *(bf16x8*)(out + (size_t)row * H_ + t * 8) = o;
}

// ------------------------------------------------------------------- GEMM
// gemmra: the round-10 WINNER restored verbatim.  128x128 tile, 4 waves
// (2Mx2N, 64x64/wave), BK=64, 2-slot double buffer (64KB -> 2 blocks/CU),
// register read-ahead (next half's ds_reads issued before current MFMA),
// ONE barrier + one vmcnt(0) per BK=64 slice.  16x16x32 MFMA.
template <int GELU, int RES, int WF, int WB, int ODYN>
__global__ __launch_bounds__(256, 2) void gemmra(const u16* __restrict__ A, const u16* __restrict__ Bt,
                                                 const float* __restrict__ bias, const float* __restrict__ res,
                                                 void* __restrict__ outF, u16* __restrict__ outB,
                                                 const int* __restrict__ flags, int Mr, int N, int K) {
  __shared__ u16 lds[32768];   // 64 KiB: slot{0,1} x (A 16KB + B 16KB)
  const int t = threadIdx.x;
  const int w = t >> 6, l = t & 63, lr = l & 15, lk = l >> 4;
  const int wr = w >> 1, wc = w & 1;
  const int gx = gridDim.x, gy = gridDim.y;
  const int orig = blockIdx.y * gx + blockIdx.x;
  const int nwg = gx * gy, per = nwg >> 3;
  int tm, tn;
  if ((gx & 7) == 0 && (per & 7) == 0) {
    const int xcd = orig & 7, p = orig >> 3;
    const int ncx = gx >> 3, cy = per >> 3;
    const int ccol = xcd % ncx, crow = xcd / ncx;
    const int px = p & 7, py = p >> 3;
    tn = (ccol * 8 + px) * 128;
    tm = (crow * cy + py) * 128;
  } else {
    tn = (orig % gx) * 128;
    tm = (orig / gx) * 128;
  }
  u32 aofs[4], bofs[4];
#pragma unroll
  for (int i = 0; i < 4; ++i) {
    const int idx = i * 256 + t;
    const int srow = idx >> 3, sc = idx & 7;
    const int lc = sc ^ (srow & 7);
    aofs[i] = (u32)(tm + srow) * (u32)K + (u32)lc * 8;
    bofs[i] = (u32)(tn + srow) * (u32)K + (u32)lc * 8;
  }
  const int wdst = w * 512;
  const int cso0 = ((0 + lk) ^ (lr & 7)) * 8;
  const int cso1 = ((4 + lk) ^ (lr & 7)) * 8;
  int arow[4], brow[4];
#pragma unroll
  for (int f = 0; f < 4; ++f) {
    arow[f] = (wr * 64 + f * 16 + lr) * 64;
    brow[f] = (wc * 64 + f * 16 + lr) * 64;
  }

  const int NS = K >> 6;
  f32x4 acc[4][4] = {};

#define STG(sl) do {                                                                                  \
    u16* Ad = lds + ((sl) & 1) * 16384;                                                               \
    u16* Bd = Ad + 8192;                                                                              \
    const u32 ko = (u32)(sl) * 64;                                                                    \
    _Pragma("unroll")                                                                                 \
    for (int i = 0; i < 4; ++i) {                                                                     \
      __builtin_amdgcn_global_load_lds(GLBP(A + aofs[i] + ko), LDSP(Ad + i * 2048 + wdst), 16, 0, 0); \
      __builtin_amdgcn_global_load_lds(GLBP(Bt + bofs[i] + ko), LDSP(Bd + i * 2048 + wdst), 16, 0, 0);\
    }                                                                                                 \
  } while (0)
#define RD(afX, bqX, sl, cso) do {                                                                    \
    const u16* As_ = lds + ((sl) & 1) * 16384;                                                        \
    const u16* Bs_ = As_ + 8192;                                                                      \
    _Pragma("unroll")                                                                                 \
    for (int f = 0; f < 4; ++f) {                                                                     \
      afX[f] = *(const bf16x8*)(As_ + arow[f] + (cso));                                               \
      bqX[f] = *(const bf16x8*)(Bs_ + brow[f] + (cso));                                               \
    }                                                                                                 \
  } while (0)
#define MM(afX, bqX)                                                                                  \
  _Pragma("unroll") for (int nf = 0; nf < 4; ++nf)                                                    \
  _Pragma("unroll") for (int mf = 0; mf < 4; ++mf)                                                    \
    acc[mf][nf] = __builtin_amdgcn_mfma_f32_16x16x32_bf16(afX[mf], bqX[nf], acc[mf][nf], 0, 0, 0);

  bf16x8 afA[4], bqA[4], afB[4], bqB[4];

  STG(0);
  asm volatile("s_waitcnt vmcnt(0)" ::: "memory");
  __builtin_amdgcn_s_barrier();
  RD(afA, bqA, 0, cso0);
  asm volatile("s_waitcnt lgkmcnt(0)" ::: "memory");
  __builtin_amdgcn_sched_barrier(0);

  for (int s = 0; s < NS; ++s) {
    if (s + 1 < NS) STG(s + 1);
    RD(afB, bqB, s, cso1);
    __builtin_amdgcn_sched_barrier(0);
    __builtin_amdgcn_s_setprio(1);
    MM(afA, bqA);
    __builtin_amdgcn_s_setprio(0);
    asm volatile("s_waitcnt lgkmcnt(0)" ::: "memory");
    __builtin_amdgcn_sched_barrier(0);
    asm volatile("s_waitcnt vmcnt(0)" ::: "memory");
    __builtin_amdgcn_s_barrier();
    if (s + 1 < NS) RD(afA, bqA, s + 1, cso0);
    __builtin_amdgcn_sched_barrier(0);
    __builtin_amdgcn_s_setprio(1);
    MM(afB, bqB);
    __builtin_amdgcn_s_setprio(0);
    asm volatile("s_waitcnt lgkmcnt(0)" ::: "memory");
    __builtin_amdgcn_sched_barrier(0);
  }
#undef STG
#undef RD
#undef MM

  const int obf = ODYN ? (flags[0] ? 0 : 1) : 0;
  (void)Mr;
#pragma unroll
  for (int mf = 0; mf < 4; ++mf) {
#pragma unroll
    for (int nf = 0; nf < 4; ++nf) {
      const int col = tn + wc * 64 + nf * 16 + lr;
      const float bv = bias[col];
#pragma unroll
      for (int j = 0; j < 4; ++j) {
        const int rw = tm + wr * 64 + mf * 16 + lk * 4 + j;
        float vv = acc[mf][nf][j] + bv;
        if (RES) vv += res[(size_t)rw * N + col];
        if (GELU) vv = geluf(vv);
        if (WF) {
          if (ODYN && obf) ((u16*)outF)[(size_t)rw * N + col] = f2b(vv);
          else ((float*)outF)[(size_t)rw * N + col] = vv;
        }
        if (WB) outB[(size_t)rw * N + col] = f2b(vv);
      }
    }
  }
}

// g32ra: A/B EXPERIMENT — identical schedule to gemmra, but 32x32x16 MFMA
// (half the MFMA instructions per FLOP; m119 issue-efficiency).  Same BK=64
// unpacked layout; swizzle changed to chunk^((row>>1)&7) so 32-lane row
// groups alias <=2-way (free); inverse applied on global source (rule #21).
// C/D mapping per verified m74/m101 formula (r5-tested).
template <int GELU, int RES, int WF, int WB, int ODYN>
__global__ __launch_bounds__(256, 2) void g32ra(const u16* __restrict__ A, const u16* __restrict__ Bt,
                                                const float* __restrict__ bias, const float* __restrict__ res,
                                                void* __restrict__ outF, u16* __restrict__ outB,
                                                const int* __restrict__ flags, int Mr, int N, int K) {
  __shared__ u16 lds[32768];
  const int t = threadIdx.x;
  const int w = t >> 6, l = t & 63, lm = l & 31, lh = l >> 5;
  const int wr = w >> 1, wc = w & 1;
  const int gx = gridDim.x, gy = gridDim.y;
  const int orig = blockIdx.y * gx + blockIdx.x;
  const int nwg = gx * gy, per = nwg >> 3;
  int tm, tn;
  if ((gx & 7) == 0 && (per & 7) == 0) {
    const int xcd = orig & 7, p = orig >> 3;
    const int ncx = gx >> 3, cy = per >> 3;
    const int ccol = xcd % ncx, crow = xcd / ncx;
    const int px = p & 7, py = p >> 3;
    tn = (ccol * 8 + px) * 128;
    tm = (crow * cy + py) * 128;
  } else {
    tn = (orig % gx) * 128;
    tm = (orig / gx) * 128;
  }
  u32 aofs[4], bofs[4];
#pragma unroll
  for (int i = 0; i < 4; ++i) {
    const int idx = i * 256 + t;
    const int srow = idx >> 3, sc = idx & 7;
    const int lc = sc ^ ((srow >> 1) & 7);
    aofs[i] = (u32)(tm + srow) * (u32)K + (u32)lc * 8;
    bofs[i] = (u32)(tn + srow) * (u32)K + (u32)lc * 8;
  }
  const int wdst = w * 512;
  // frag offsets: row R, chunk = ks*2+lh, swz chunk^((R>>1)&7)
  int offA[2][4], offB[2][4];
#pragma unroll
  for (int mi = 0; mi < 2; ++mi)
#pragma unroll
    for (int ks = 0; ks < 4; ++ks) {
      const int Ra = wr * 64 + mi * 32 + lm;
      offA[mi][ks] = Ra * 64 + (((ks * 2 + lh) ^ ((Ra >> 1) & 7)) << 3);
      const int Rb = wc * 64 + mi * 32 + lm;
      offB[mi][ks] = Rb * 64 + (((ks * 2 + lh) ^ ((Rb >> 1) & 7)) << 3);
    }

  const int NS = K >> 6;
  f32x16 acc[2][2] = {};

#define STG(sl) do {                                                                                  \
    u16* Ad = lds + ((sl) & 1) * 16384;                                                               \
    u16* Bd = Ad + 8192;                                                                              \
    const u32 ko = (u32)(sl) * 64;                                                                    \
    _Pragma("unroll")                                                                                 \
    for (int i = 0; i < 4; ++i) {                                                                     \
      __builtin_amdgcn_global_load_lds(GLBP(A + aofs[i] + ko), LDSP(Ad + i * 2048 + wdst), 16, 0, 0); \
      __builtin_amdgcn_global_load_lds(GLBP(Bt + bofs[i] + ko), LDSP(Bd + i * 2048 + wdst), 16, 0, 0);\
    }                                                                                                 \
  } while (0)
#define RD(afX, bqX, sl, half) do {                                                                   \
    const u16* As_ = lds + ((sl) & 1) * 16384;                                                        \
    const u16* Bs_ = As_ + 8192;                                                                      \
    _Pragma("unroll")                                                                                 \
    for (int mi = 0; mi < 2; ++mi)                                                                    \
    _Pragma("unroll")                                                                                 \
      for (int k2 = 0; k2 < 2; ++k2) {                                                                \
        afX[mi][k2] = *(const bf16x8*)(As_ + offA[mi][(half) * 2 + k2]);                              \
        bqX[mi][k2] = *(const bf16x8*)(Bs_ + offB[mi][(half) * 2 + k2]);                              \
      }                                                                                               \
  } while (0)
#define MM(afX, bqX)                                                                                  \
  _Pragma("unroll") for (int k2 = 0; k2 < 2; ++k2)                                                    \
  _Pragma("unroll") for (int mi = 0; mi < 2; ++mi)                                                    \
  _Pragma("unroll") for (int ni = 0; ni < 2; ++ni)                                                    \
    acc[mi][ni] = __builtin_amdgcn_mfma_f32_32x32x16_bf16(afX[mi][k2], bqX[ni][k2], acc[mi][ni], 0, 0, 0);

  bf16x8 afA[2][2], bqA[2][2], afB[2][2], bqB[2][2];

  STG(0);
  asm volatile("s_waitcnt vmcnt(0)" ::: "memory");
  __builtin_amdgcn_s_barrier();
  RD(afA, bqA, 0, 0);
  asm volatile("s_waitcnt lgkmcnt(0)" ::: "memory");
  __builtin_amdgcn_sched_barrier(0);

  for (int s = 0; s < NS; ++s) {
    if (s + 1 < NS) STG(s + 1);
    RD(afB, bqB, s, 1);
    __builtin_amdgcn_sched_barrier(0);
    __builtin_amdgcn_s_setprio(1);
    MM(afA, bqA);
    __builtin_amdgcn_s_setprio(0);
    asm volatile("s_waitcnt lgkmcnt(0)" ::: "memory");
    __builtin_amdgcn_sched_barrier(0);
    asm volatile("s_waitcnt vmcnt(0)" ::: "memory");
    __builtin_amdgcn_s_barrier();
    if (s + 1 < NS) RD(afA, bqA, s + 1, 0);
    __builtin_amdgcn_sched_barrier(0);
    __builtin_amdgcn_s_setprio(1);
    MM(afB, bqB);
    __builtin_amdgcn_s_setprio(0);
    asm volatile("s_waitcnt lgkmcnt(0)" ::: "memory");
    __builtin_amdgcn_sched_barrier(0);
  }
#undef STG
#undef RD
#undef MM

  const int obf = ODYN ? (flags[0] ? 0 : 1) : 0;
  (void)Mr;
#pragma unroll
  for (int mi = 0; mi < 2; ++mi) {
#pragma unroll
    for (int ni = 0; ni < 2; ++ni) {
      const int col = tn + wc * 64 + ni * 32 + lm;
      const float bv = bias[col];
#pragma unroll
      for (int r = 0; r < 16; ++r) {
        const int rw = tm + wr * 64 + mi * 32 + (r & 3) + 8 * (r >> 2) + 4 * lh;
        float vv = acc[mi][ni][r] + bv;
        if (RES) vv += res[(size_t)rw * N + col];
        if (GELU) vv = geluf(vv);
        if (WF) {
          if (ODYN && obf) ((u16*)outF)[(size_t)rw * N + col] = f2b(vv);
          else ((float*)outF)[(size_t)rw * N + col] = vv;
        }
        if (WB) outB[(size_t)rw * N + col] = f2b(vv);
      }
    }
  }
}

// --------------------------------------------------------------- l2 norms
__global__ __launch_bounds__(256) void l2_q(const float* __restrict__ qpre, u16* __restrict__ Q) {
  const int t = threadIdx.x;
  const int g = blockIdx.x * 64 + (t >> 2);
  const int lg = t & 3;
  const int h = g & (NH_ - 1), sb = g >> 4;
  const float* p = qpre + (size_t)sb * H_ + h * D_ + lg * 32;
  float vv[32];
  float ss = 0.f;
#pragma unroll
  for (int i = 0; i < 8; ++i) {
    float4 a = *(const float4*)&p[i * 4];
    vv[i * 4 + 0] = a.x; vv[i * 4 + 1] = a.y; vv[i * 4 + 2] = a.z; vv[i * 4 + 3] = a.w;
    ss += a.x * a.x + a.y * a.y + a.z * a.z + a.w * a.w;
  }
  ss += __shfl_xor(ss, 1); ss += __shfl_xor(ss, 2);
  const float sc = rsqrtf(ss + 1e-12f);
  const int s = sb >> 1, b = sb & 1;
  u16* o = Q + ((size_t)(b * NH_ + h) * S_ + s) * D_ + lg * 32;
#pragma unroll
  for (int i = 0; i < 4; ++i) {
    bf16x8 ov;
#pragma unroll
    for (int j = 0; j < 8; ++j) ov[j] = (short)f2b(vv[i * 8 + j] * sc);
    *(bf16x8*)&o[i * 8] = ov;
  }
}

__global__ __launch_bounds__(256) void l2_kv(const float* __restrict__ kvpre, u16* __restrict__ Kq, u16* __restrict__ Vt) {
  __shared__ u16 vtT[128][72];
  const int t = threadIdx.x;
  const int bid = blockIdx.x;
  const int mt = bid & 31, h = (bid >> 5) & 15, b = bid >> 9;
  const int lm = t >> 2, lg = t & 3;
  const int m = mt * 64 + lm;
  const size_t rowoff = (size_t)(m * B_ + b) * (2 * H_) + h * 256;
  float vv[32];
  { // K half
    const float* p = kvpre + rowoff + lg * 32;
    float ss = 0.f;
#pragma unroll
    for (int i = 0; i < 8; ++i) {
      float4 a = *(const float4*)&p[i * 4];
      vv[i * 4 + 0] = a.x; vv[i * 4 + 1] = a.y; vv[i * 4 + 2] = a.z; vv[i * 4 + 3] = a.w;
      ss += a.x * a.x + a.y * a.y + a.z * a.z + a.w * a.w;
    }
    ss += __shfl_xor(ss, 1); ss += __shfl_xor(ss, 2);
    const float sc = rsqrtf(ss + 1e-12f);
    u16* o = Kq + ((size_t)(b * NH_ + h) * M_ + m) * D_ + lg * 32;
#pragma unroll
    for (int i = 0; i < 4; ++i) {
      bf16x8 ov;
#pragma unroll
      for (int j = 0; j < 8; ++j) ov[j] = (short)f2b(vv[i * 8 + j] * sc);
      *(bf16x8*)&o[i * 8] = ov;
    }
  }
  { // V half -> LDS transposed
    const float* p = kvpre + rowoff + 128 + lg * 32;
    float ss = 0.f;
#pragma unroll
    for (int i = 0; i < 8; ++i) {
      float4 a = *(const float4*)&p[i * 4];
      vv[i * 4 + 0] = a.x; vv[i * 4 + 1] = a.y; vv[i * 4 + 2] = a.z; vv[i * 4 + 3] = a.w;
      ss += a.x * a.x + a.y * a.y + a.z * a.z + a.w * a.w;
    }
    ss += __shfl_xor(ss, 1); ss += __shfl_xor(ss, 2);
    const float sc = rsqrtf(ss + 1e-12f);
#pragma unroll
    for (int i = 0; i < 32; ++i) vtT[lg * 32 + i][lm] = f2b(vv[i] * sc);
  }
  __syncthreads();
  const int d = t >> 1, half = t & 1;
  u16* o = Vt + ((size_t)(b * NH_ + h) * D_ + d) * M_ + mt * 64 + half * 32;
#pragma unroll
  for (int i = 0; i < 4; ++i) {
    bf16x8 ov = *(const bf16x8*)&vtT[d][half * 32 + i * 8];
    *(bf16x8*)&o[i * 8] = ov;
  }
}

// -------------------------------------------------------------- attention
// unchanged (verified; ~130 us)
__global__ __launch_bounds__(256, 3) void attn_k(const u16* __restrict__ Q, const u16* __restrict__ Kq,
                                                 const u16* __restrict__ Vt, const u32* __restrict__ BM32,
                                                 u16* __restrict__ ctx) {
  __shared__ u16 Kl[2][4096];
  __shared__ u16 Vl[2][4096];
  __shared__ u16 Pl[4][16 * 40];
  const int t = threadIdx.x, w = t >> 6, l = t & 63, lr = l & 15, lk = l >> 4;
  const int lin = blockIdx.x;
  const int xcd = lin & 7, idx = lin >> 3;
  const int bh = xcd * 4 + (idx >> 5);
  const int chunk = idx & 31;
  const int b = bh >> 4, h = bh & 15;
  const int srow = chunk * 64 + w * 16;
  const u16* Qb = Q + ((size_t)bh * S_ + srow) * D_;
  bf16x8 qf[4];
#pragma unroll
  for (int kc = 0; kc < 4; ++kc)
    qf[kc] = *(const bf16x8*)&Qb[lr * D_ + kc * 32 + lk * 8];
  f32x4 oacc[8] = {};
  float den[4] = {};
  const u16* Kb = Kq + (size_t)bh * M_ * D_;
  const u16* Vb = Vt + (size_t)bh * D_ * M_;
  const float invn = 0.08838834764831845f;
  u32 ksrc[2], vsrc[2];
#pragma unroll
  for (int i = 0; i < 2; ++i) {
    const int kidx = i * 256 + t;
    const int kr = kidx >> 4, kc_ = (kidx & 15) ^ (kr & 7);
    ksrc[i] = (u32)kr * D_ + (u32)kc_ * 8;
    const int vidx = i * 256 + t;
    const int vd = vidx >> 2, vc = (vidx & 3) ^ ((vd >> 1) & 3);
    vsrc[i] = (u32)vd * M_ + (u32)vc * 8;
  }
  const int wdst = w * 64 * 8;
  u32 mrow[4];
#pragma unroll
  for (int j2 = 0; j2 < 4; ++j2)
    mrow[j2] = ((u32)b * S_ + (u32)(srow + lk * 4 + j2)) * 64u;

#define STG(buf, m0) do {                                                                              \
    _Pragma("unroll")                                                                                  \
    for (int i = 0; i < 2; ++i) {                                                                      \
      __builtin_amdgcn_global_load_lds(GLBP(Kb + (size_t)(m0) * D_ + ksrc[i]),                         \
                                       LDSP(&Kl[buf][i * 2048 + wdst]), 16, 0, 0);                     \
      __builtin_amdgcn_global_load_lds(GLBP(Vb + (size_t)(m0) + vsrc[i]),                              \
                                       LDSP(&Vl[buf][i * 2048 + wdst]), 16, 0, 0);                     \
    }                                                                                                  \
  } while (0)

  STG(0, 0);
  asm volatile("s_waitcnt vmcnt(0)" ::: "memory");
  __builtin_amdgcn_s_barrier();
  int cur = 0;

  for (int t64 = 0; t64 < M_ / 32; ++t64) {
    const int m0 = t64 * 32;
    if (t64 + 1 < M_ / 32) STG(cur ^ 1, m0 + 32);
    u32 mw[4];
#pragma unroll
    for (int j2 = 0; j2 < 4; ++j2) mw[j2] = BM32[mrow[j2] + t64];
    f32x4 sc[2] = {};
#pragma unroll
    for (int mf = 0; mf < 2; ++mf) {
      const int r = mf * 16 + lr;
#pragma unroll
      for (int kc = 0; kc < 4; ++kc) {
        const int cc = ((kc * 4 + lk) ^ (r & 7));
        bf16x8 kfv = *(const bf16x8*)&Kl[cur][r * 128 + cc * 8];
        sc[mf] = __builtin_amdgcn_mfma_f32_16x16x32_bf16(qf[kc], kfv, sc[mf], 0, 0, 0);
      }
    }
#pragma unroll
    for (int j2 = 0; j2 < 4; ++j2) {
      const int rloc = lk * 4 + j2;
#pragma unroll
      for (int mf = 0; mf < 2; ++mf) {
        float p = __expf(sc[mf][j2] * invn);
        p = ((mw[j2] >> (mf * 16 + lr)) & 1u) ? p : 0.0f;
        den[j2] += p;
        Pl[w][rloc * 40 + mf * 16 + lr] = f2b(p);
      }
    }
    asm volatile("s_waitcnt lgkmcnt(0)" ::: "memory");
    __builtin_amdgcn_sched_barrier(0);
    bf16x8 pa = *(const bf16x8*)&Pl[w][lr * 40 + lk * 8];
#pragma unroll
    for (int nf = 0; nf < 8; ++nf) {
      const int d = nf * 16 + lr;
      const int cc = lk ^ ((d >> 1) & 3);
      bf16x8 vfv = *(const bf16x8*)&Vl[cur][d * 32 + cc * 8];
      oacc[nf] = __builtin_amdgcn_mfma_f32_16x16x32_bf16(pa, vfv, oacc[nf], 0, 0, 0);
    }
    asm volatile("s_waitcnt vmcnt(0)" ::: "memory");
    __builtin_amdgcn_s_barrier();
    cur ^= 1;
  }
#undef STG
#pragma unroll
  for (int j2 = 0; j2 < 4; ++j2) {
    float d = den[j2];
    d += __shfl_xor(d, 1); d += __shfl_xor(d, 2); d += __shfl_xor(d, 4); d += __shfl_xor(d, 8);
    den[j2] = 1.0f / fmaxf(d, 1e-20f);
  }
#pragma unroll
  for (int nf = 0; nf < 8; ++nf)
#pragma unroll
    for (int j2 = 0; j2 < 4; ++j2) {
      const int s = srow + lk * 4 + j2;
      const int dd = nf * 16 + lr;
      ctx[((size_t)s * B_ + b) * H_ + h * D_ + dd] = f2b(oacc[nf][j2] * den[j2]);
    }
}

// ------------------------------------------------------------------- host
extern "C" void kernel_launch(void* const* d_in, const int* in_sizes, int n_in,
                              void* d_out, int out_size, void* d_ws, size_t ws_size,
                              hipStream_t stream) {
  (void)in_sizes; (void)n_in; (void)out_size; (void)ws_size;
  char* ws = (char*)d_ws;
  u16* WT     = (u16*)(ws + 0);
  void* MID   = (void*)(ws + 33554432);
  float* XF   = (float*)(ws + 100663296);
  u16* HB     = (u16*)(ws + 134217728);
  u16* MEMB   = (u16*)(ws + 150994944);
  u16* QB     = (u16*)(ws + 167772160);
  u16* KB     = (u16*)(ws + 184549376);
  u16* VTB    = (u16*)(ws + 201326592);
  u64* BMB    = (u64*)(ws + 218103808);
  float* SM   = (float*)(ws + 234881024);
  int* FLAGS  = (int*)(ws + 235044864);

  float* Bias1  = SM + 0;
  float* Bias1o = SM + 8192;
  float* BiasQ  = SM + 10240;
  float* BiasKV = SM + 12288;
  float* BiasD  = SM + 16384;
  float* Bias2  = SM + 18432;
  float* Bias2o = SM + 26624;
  float* G1v = SM + 28672; float* B1v = SM + 30720;
  float* G2v = SM + 32768; float* B2v = SM + 34816;
  float* G3v = SM + 36864; float* B3v = SM + 38912;

  detect_kinds<<<1, 64, 0, stream>>>((const u32*)d_in[0], (const u32*)d_in[2], FLAGS);

  cvt_all<<<160, 256, 0, stream>>>(d_in[10], d_in[12], d_in[14], d_in[16], d_in[18],
                                   d_in[20], d_in[22], d_in[3], d_in[4], d_in[5],
                                   d_in[6], d_in[7], d_in[8], FLAGS, SM);

  mask_bits<<<(B_ * S_ * M_) / 256, 256, 0, stream>>>(d_in[2], FLAGS, BMB);
  cast_in_bf16<<<(MB_ * H_ / 8) / 256, 256, 0, stream>>>(d_in[1], FLAGS, MEMB, MB_ * H_ / 8);

  dim3 blk(256);
  // ---- mlp1  (A/B: g32ra on the GELU GEMM)
  layernorm_k<1><<<SB_, blk, 0, stream>>>(d_in[0], FLAGS, G1v, B1v, HB);
  transpose_cast<<<dim3(FF_ / 64, H_ / 64), blk, 0, stream>>>(d_in[9], FLAGS, WT, H_, FF_);
  g32ra<1, 0, 0, 1, 0><<<dim3(FF_ / 128, SB_ / 128), blk, 0, stream>>>(HB, WT, Bias1, nullptr, nullptr, (u16*)MID, FLAGS, SB_, FF_, H_);
  transpose_cast<<<dim3(H_ / 64, FF_ / 64), blk, 0, stream>>>(d_in[11], FLAGS, WT, FF_, H_);
  gemmra<0, 0, 1, 0, 0><<<dim3(H_ / 128, SB_ / 128), blk, 0, stream>>>((u16*)MID, WT, Bias1o, nullptr, XF, nullptr, FLAGS, SB_, H_, FF_);

  // ---- memory attention
  layernorm_k<0><<<SB_, blk, 0, stream>>>(XF, FLAGS, G2v, B2v, HB);
  transpose_cast<<<dim3(H_ / 64, H_ / 64), blk, 0, stream>>>(d_in[13], FLAGS, WT, H_, H_);
  gemmra<0, 0, 1, 0, 0><<<dim3(H_ / 128, SB_ / 128), blk, 0, stream>>>(HB, WT, BiasQ, nullptr, MID, nullptr, FLAGS, SB_, H_, H_);
  l2_q<<<(SB_ * NH_) / 64, blk, 0, stream>>>((const float*)MID, QB);
  transpose_cast<<<dim3(2 * H_ / 64, H_ / 64), blk, 0, stream>>>(d_in[15], FLAGS, WT, H_, 2 * H_);
  gemmra<0, 0, 1, 0, 0><<<dim3(2 * H_ / 128, MB_ / 128), blk, 0, stream>>>(MEMB, WT, BiasKV, nullptr, MID, nullptr, FLAGS, MB_, 2 * H_, H_);
  l2_kv<<<B_ * NH_ * (M_ / 64), blk, 0, stream>>>((const float*)MID, KB, VTB);
  attn_k<<<1024, blk, 0, stream>>>(QB, KB, VTB, (const u32*)BMB, MEMB);
  transpose_cast<<<dim3(H_ / 64, H_ / 64), blk, 0, stream>>>(d_in[17], FLAGS, WT, H_, H_);
  gemmra<0, 1, 1, 0, 0><<<dim3(H_ / 128, SB_ / 128), blk, 0, stream>>>(MEMB, WT, BiasD, XF, XF, nullptr, FLAGS, SB_, H_, H_);

  // ---- mlp2  (A/B: g32ra on the GELU GEMM)
  layernorm_k<0><<<SB_, blk, 0, stream>>>(XF, FLAGS, G3v, B3v, HB);
  transpose_cast<<<dim3(FF_ / 64, H_ / 64), blk, 0, stream>>>(d_in[19], FLAGS, WT, H_, FF_);
  g32ra<1, 0, 0, 1, 0><<<dim3(FF_ / 128, SB_ / 128), blk, 0, stream>>>(HB, WT, Bias2, nullptr, nullptr, (u16*)MID, FLAGS, SB_, FF_, H_);
  transpose_cast<<<dim3(H_ / 64, FF_ / 64), blk, 0, stream>>>(d_in[21], FLAGS, WT, FF_, H_);
  gemmra<0, 1, 1, 0, 1><<<dim3(H_ / 128, SB_ / 128), blk, 0, stream>>>((u16*)MID, WT, Bias2o, XF, d_out, nullptr, FLAGS, SB_, H_, FF_);
}

// Round 13
// 1135.584 us; speedup vs baseline: 1.1083x; 1.0332x over previous
//
#include <hip/hip_runtime.h>
#include <stdint.h>
#include <stddef.h>

typedef __attribute__((ext_vector_type(8))) short bf16x8;
typedef __attribute__((ext_vector_type(4))) float f32x4;
typedef unsigned short u16;
typedef unsigned int u32;
typedef unsigned long long u64;

static constexpr int S_ = 2048, B_ = 2, H_ = 2048, NH_ = 16, D_ = 128, M_ = 2048, FF_ = 8192;
static constexpr int SB_ = S_ * B_;
static constexpr int MB_ = M_ * B_;

__device__ __forceinline__ float b2f(u16 b) {
  union { u32 u; float f; } v; v.u = ((u32)b) << 16; return v.f;
}
__device__ __forceinline__ u16 f2b(float f) {
  union { float f; u32 u; } v; v.f = f;
  u32 u = v.u;
  return (u16)((u + 0x7FFFu + ((u >> 16) & 1u)) >> 16);
}
__device__ __forceinline__ float geluf(float x) {
  float x3 = x * x * x;
  return 0.5f * x * (1.0f + tanhf(0.7978845608028654f * (x + 0.044715f * x3)));
}

#define LDSP(p) (reinterpret_cast<__attribute__((address_space(3))) uint32_t*>(reinterpret_cast<uintptr_t>(p)))
#define GLBP(p) (reinterpret_cast<const __attribute__((address_space(1))) uint32_t*>(reinterpret_cast<uintptr_t>(p)))

// ---------------------------------------------------------------- detectors
__global__ void detect_kinds(const u32* __restrict__ x0, const u32* __restrict__ mask, int* __restrict__ flags) {
  if (threadIdx.x == 0 && blockIdx.x == 0) {
    int cnt = 0;
    for (int i = 0; i < 256; ++i) {
      u32 e = (x0[i] >> 7) & 0xFFu;
      if (e >= 118u && e <= 130u) ++cnt;
    }
    flags[0] = (cnt >= 128) ? 0 : 1;
    int all01 = 1, allf = 1, allb = 1;
    for (int i = 0; i < 256; ++i) {
      u32 v = mask[i];
      if (v > 1u) all01 = 0;
      if (v != 0u && v != 0x3F800000u) allf = 0;
      u32 lo = v & 0xFFFFu, hi = v >> 16;
      if ((lo != 0u && lo != 0x3F80u) || (hi != 0u && hi != 0x3F80u)) allb = 0;
    }
    flags[1] = all01 ? 1 : (allf ? 3 : (allb ? 2 : 0));
  }
}

// mask -> packed bitmask: bit m = 1 iff UNMASKED
__global__ void mask_bits(const void* __restrict__ mraw, const int* __restrict__ flags, u64* __restrict__ bm) {
  int i = blockIdx.x * 256 + threadIdx.x;
  int kind = flags[1];
  int masked;
  if (kind == 1)      masked = ((const int*)mraw)[i] != 0;
  else if (kind == 3) masked = ((const float*)mraw)[i] != 0.0f;
  else if (kind == 2) masked = ((const u16*)mraw)[i] != 0;
  else                masked = ((const unsigned char*)mraw)[i] != 0;
  u64 vote = __ballot(masked == 0);
  if ((threadIdx.x & 63) == 0) bm[i >> 6] = vote;
}

// one launch for all 13 small f32 param conversions
__global__ void cvt_all(const void* s0, const void* s1, const void* s2, const void* s3,
                        const void* s4, const void* s5, const void* s6, const void* s7,
                        const void* s8, const void* s9, const void* s10, const void* s11,
                        const void* s12, const int* __restrict__ flags, float* __restrict__ SM) {
  const int i = blockIdx.x * 256 + threadIdx.x;
  if (i >= 40960) return;
  const void* src; int off;
  if (i < 8192)       { src = s0;  off = 0; }
  else if (i < 10240) { src = s1;  off = 8192; }
  else if (i < 12288) { src = s2;  off = 10240; }
  else if (i < 16384) { src = s3;  off = 12288; }
  else if (i < 18432) { src = s4;  off = 16384; }
  else if (i < 26624) { src = s5;  off = 18432; }
  else if (i < 28672) { src = s6;  off = 26624; }
  else if (i < 30720) { src = s7;  off = 28672; }
  else if (i < 32768) { src = s8;  off = 30720; }
  else if (i < 34816) { src = s9;  off = 32768; }
  else if (i < 36864) { src = s10; off = 34816; }
  else if (i < 38912) { src = s11; off = 36864; }
  else                { src = s12; off = 38912; }
  const int j = i - off;
  SM[i] = flags[0] ? ((const float*)src)[j] : b2f(((const u16*)src)[j]);
}

__global__ void cast_in_bf16(const void* __restrict__ src, const int* __restrict__ flags, u16* __restrict__ dst, int n8) {
  int i = blockIdx.x * 256 + threadIdx.x;
  if (i >= n8) return;
  if (flags[0]) {
    const float4* p = (const float4*)src;
    float4 a = p[i * 2], c = p[i * 2 + 1];
    bf16x8 o;
    o[0] = (short)f2b(a.x); o[1] = (short)f2b(a.y); o[2] = (short)f2b(a.z); o[3] = (short)f2b(a.w);
    o[4] = (short)f2b(c.x); o[5] = (short)f2b(c.y); o[6] = (short)f2b(c.z); o[7] = (short)f2b(c.w);
    *(bf16x8*)&dst[i * 8] = o;
  } else {
    *(bf16x8*)&dst[i * 8] = ((const bf16x8*)src)[i];
  }
}

// ------------------------------------------------------------ transpose+cast
__global__ __launch_bounds__(256) void transpose_cast(const void* __restrict__ in, const int* __restrict__ flags,
                                                      u16* __restrict__ out, int R, int C) {
  __shared__ u16 tile[64][65];
  const int isf = flags[0];
  const int tr = blockIdx.y * 64, tc = blockIdx.x * 64;
  const int tx = threadIdx.x & 63, ty = threadIdx.x >> 6;
  const float* inf = (const float*)in;
  const u16* inb = (const u16*)in;
#pragma unroll
  for (int i = 0; i < 16; ++i) {
    int r = ty * 16 + i;
    size_t idx = (size_t)(tr + r) * C + tc + tx;
    tile[r][tx] = isf ? f2b(inf[idx]) : inb[idx];
  }
  __syncthreads();
#pragma unroll
  for (int i = 0; i < 16; ++i) {
    int c = ty * 16 + i;
    out[(size_t)(tc + c) * R + tr + tx] = tile[tx][c];
  }
}

// ---------------------------------------------------------------- layernorm
template <int EXT>
__global__ __launch_bounds__(256) void layernorm_k(const void* __restrict__ xin, const int* __restrict__ flags,
                                                   const float* __restrict__ g, const float* __restrict__ bta,
                                                   u16* __restrict__ out) {
  const int row = blockIdx.x, t = threadIdx.x;
  float v[8];
  bool bfmode = EXT && (flags[0] == 0);
  if (bfmode) {
    const u16* xr = (const u16*)xin + (size_t)row * H_ + t * 8;
    bf16x8 a = *(const bf16x8*)xr;
#pragma unroll
    for (int j = 0; j < 8; ++j) v[j] = b2f((u16)a[j]);
  } else {
    const float* xr = (const float*)xin + (size_t)row * H_ + t * 8;
    float4 a = *(const float4*)xr, c = *(const float4*)(xr + 4);
    v[0] = a.x; v[1] = a.y; v[2] = a.z; v[3] = a.w;
    v[4] = c.x; v[5] = c.y; v[6] = c.z; v[7] = c.w;
  }
  float s1 = 0.f, s2 = 0.f;
#pragma unroll
  for (int j = 0; j < 8; ++j) { s1 += v[j]; s2 += v[j] * v[j]; }
#pragma unroll
  for (int off = 32; off > 0; off >>= 1) { s1 += __shfl_down(s1, off); s2 += __shfl_down(s2, off); }
  __shared__ float red[8];
  const int w = t >> 6;
  if ((t & 63) == 0) { red[w] = s1; red[4 + w] = s2; }
  __syncthreads();
  s1 = red[0] + red[1] + red[2] + red[3];
  s2 = red[4] + red[5] + red[6] + red[7];
  const float mean = s1 * (1.0f / H_);
  const float rstd = rsqrtf(s2 * (1.0f / H_) - mean * mean + 1e-5f);
  bf16x8 o;
#pragma unroll
  for (int j = 0; j < 8; ++j) {
    float y = (v[j] - mean) * rstd * g[t * 8 + j] + bta[t * 8 + j];
    o[j] = (short)f2b(y);
  }
  *(bf16x8*)(out + (size_t)row * H_ + t * 8) = o;
}

// ------------------------------------------------------------------- GEMM
// gemmra: round-10 winner (208us FF).  128x128 tile, 4 waves (2Mx2N,
// 64x64/wave), BK=64, 2-slot double buffer (64KB -> 2 blocks/CU),
// register read-ahead, ONE barrier + one vmcnt(0) per slice.  16x16x32 MFMA.
template <int GELU, int RES, int WF, int WB, int ODYN>
__global__ __launch_bounds__(256, 2) void gemmra(const u16* __restrict__ A, const u16* __restrict__ Bt,
                                                 const float* __restrict__ bias, const float* __restrict__ res,
                                                 void* __restrict__ outF, u16* __restrict__ outB,
                                                 const int* __restrict__ flags, int Mr, int N, int K) {
  __shared__ u16 lds[32768];   // 64 KiB
  const int t = threadIdx.x;
  const int w = t >> 6, l = t & 63, lr = l & 15, lk = l >> 4;
  const int wr = w >> 1, wc = w & 1;
  const int gx = gridDim.x, gy = gridDim.y;
  const int orig = blockIdx.y * gx + blockIdx.x;
  const int nwg = gx * gy, per = nwg >> 3;
  int tm, tn;
  if ((gx & 7) == 0 && (per & 7) == 0) {
    const int xcd = orig & 7, p = orig >> 3;
    const int ncx = gx >> 3, cy = per >> 3;
    const int ccol = xcd % ncx, crow = xcd / ncx;
    const int px = p & 7, py = p >> 3;
    tn = (ccol * 8 + px) * 128;
    tm = (crow * cy + py) * 128;
  } else {
    tn = (orig % gx) * 128;
    tm = (orig / gx) * 128;
  }
  u32 aofs[4], bofs[4];
#pragma unroll
  for (int i = 0; i < 4; ++i) {
    const int idx = i * 256 + t;
    const int srow = idx >> 3, sc = idx & 7;
    const int lc = sc ^ (srow & 7);
    aofs[i] = (u32)(tm + srow) * (u32)K + (u32)lc * 8;
    bofs[i] = (u32)(tn + srow) * (u32)K + (u32)lc * 8;
  }
  const int wdst = w * 512;
  const int cso0 = ((0 + lk) ^ (lr & 7)) * 8;
  const int cso1 = ((4 + lk) ^ (lr & 7)) * 8;
  int arow[4], brow[4];
#pragma unroll
  for (int f = 0; f < 4; ++f) {
    arow[f] = (wr * 64 + f * 16 + lr) * 64;
    brow[f] = (wc * 64 + f * 16 + lr) * 64;
  }

  const int NS = K >> 6;
  f32x4 acc[4][4] = {};

#define STG(sl) do {                                                                                  \
    u16* Ad = lds + ((sl) & 1) * 16384;                                                               \
    u16* Bd = Ad + 8192;                                                                              \
    const u32 ko = (u32)(sl) * 64;                                                                    \
    _Pragma("unroll")                                                                                 \
    for (int i = 0; i < 4; ++i) {                                                                     \
      __builtin_amdgcn_global_load_lds(GLBP(A + aofs[i] + ko), LDSP(Ad + i * 2048 + wdst), 16, 0, 0); \
      __builtin_amdgcn_global_load_lds(GLBP(Bt + bofs[i] + ko), LDSP(Bd + i * 2048 + wdst), 16, 0, 0);\
    }                                                                                                 \
  } while (0)
#define RD(afX, bqX, sl, cso) do {                                                                    \
    const u16* As_ = lds + ((sl) & 1) * 16384;                                                        \
    const u16* Bs_ = As_ + 8192;                                                                      \
    _Pragma("unroll")                                                                                 \
    for (int f = 0; f < 4; ++f) {                                                                     \
      afX[f] = *(const bf16x8*)(As_ + arow[f] + (cso));                                               \
      bqX[f] = *(const bf16x8*)(Bs_ + brow[f] + (cso));                                               \
    }                                                                                                 \
  } while (0)
#define MM(afX, bqX)                                                                                  \
  _Pragma("unroll") for (int nf = 0; nf < 4; ++nf)                                                    \
  _Pragma("unroll") for (int mf = 0; mf < 4; ++mf)                                                    \
    acc[mf][nf] = __builtin_amdgcn_mfma_f32_16x16x32_bf16(afX[mf], bqX[nf], acc[mf][nf], 0, 0, 0);

  bf16x8 afA[4], bqA[4], afB[4], bqB[4];

  STG(0);
  asm volatile("s_waitcnt vmcnt(0)" ::: "memory");
  __builtin_amdgcn_s_barrier();
  RD(afA, bqA, 0, cso0);
  asm volatile("s_waitcnt lgkmcnt(0)" ::: "memory");
  __builtin_amdgcn_sched_barrier(0);

  for (int s = 0; s < NS; ++s) {
    if (s + 1 < NS) STG(s + 1);
    RD(afB, bqB, s, cso1);
    __builtin_amdgcn_sched_barrier(0);
    __builtin_amdgcn_s_setprio(1);
    MM(afA, bqA);
    __builtin_amdgcn_s_setprio(0);
    asm volatile("s_waitcnt lgkmcnt(0)" ::: "memory");
    __builtin_amdgcn_sched_barrier(0);
    asm volatile("s_waitcnt vmcnt(0)" ::: "memory");
    __builtin_amdgcn_s_barrier();
    if (s + 1 < NS) RD(afA, bqA, s + 1, cso0);
    __builtin_amdgcn_sched_barrier(0);
    __builtin_amdgcn_s_setprio(1);
    MM(afB, bqB);
    __builtin_amdgcn_s_setprio(0);
    asm volatile("s_waitcnt lgkmcnt(0)" ::: "memory");
    __builtin_amdgcn_sched_barrier(0);
  }
#undef STG
#undef RD
#undef MM

  const int obf = ODYN ? (flags[0] ? 0 : 1) : 0;
  (void)Mr;
#pragma unroll
  for (int mf = 0; mf < 4; ++mf) {
#pragma unroll
    for (int nf = 0; nf < 4; ++nf) {
      const int col = tn + wc * 64 + nf * 16 + lr;
      const float bv = bias[col];
#pragma unroll
      for (int j = 0; j < 4; ++j) {
        const int rw = tm + wr * 64 + mf * 16 + lk * 4 + j;
        float vv = acc[mf][nf][j] + bv;
        if (RES) vv += res[(size_t)rw * N + col];
        if (GELU) vv = geluf(vv);
        if (WF) {
          if (ODYN && obf) ((u16*)outF)[(size_t)rw * N + col] = f2b(vv);
          else ((float*)outF)[(size_t)rw * N + col] = vv;
        }
        if (WB) outB[(size_t)rw * N + col] = f2b(vv);
      }
    }
  }
}

// gemmra512: A/B EXPERIMENT — same tile/schedule/layout as gemmra but 512
// threads = 8 waves (2M x 4N, per-wave 64x32 out).  Same 64KB LDS -> still
// 2 blocks/CU, but 16 waves/CU (4/SIMD vs 2/SIMD): tests whether the
// per-slice vmcnt+barrier exposure is filled by TLP (m114).
template <int GELU, int RES, int WF, int WB, int ODYN>
__global__ __launch_bounds__(512, 2) void gemmra512(const u16* __restrict__ A, const u16* __restrict__ Bt,
                                                    const float* __restrict__ bias, const float* __restrict__ res,
                                                    void* __restrict__ outF, u16* __restrict__ outB,
                                                    const int* __restrict__ flags, int Mr, int N, int K) {
  __shared__ u16 lds[32768];   // 64 KiB
  const int t = threadIdx.x;
  const int w = t >> 6, l = t & 63, lr = l & 15, lk = l >> 4;
  const int wr = w >> 2, wc = w & 3;
  const int gx = gridDim.x, gy = gridDim.y;
  const int orig = blockIdx.y * gx + blockIdx.x;
  const int nwg = gx * gy, per = nwg >> 3;
  int tm, tn;
  if ((gx & 7) == 0 && (per & 7) == 0) {
    const int xcd = orig & 7, p = orig >> 3;
    const int ncx = gx >> 3, cy = per >> 3;
    const int ccol = xcd % ncx, crow = xcd / ncx;
    const int px = p & 7, py = p >> 3;
    tn = (ccol * 8 + px) * 128;
    tm = (crow * cy + py) * 128;
  } else {
    tn = (orig % gx) * 128;
    tm = (orig / gx) * 128;
  }
  // staging: 1024 chunks per operand per slice, 512 threads -> 2 rounds
  u32 aofs[2], bofs[2];
#pragma unroll
  for (int i = 0; i < 2; ++i) {
    const int idx = i * 512 + t;
    const int srow = idx >> 3, sc = idx & 7;
    const int lc = sc ^ (srow & 7);
    aofs[i] = (u32)(tm + srow) * (u32)K + (u32)lc * 8;
    bofs[i] = (u32)(tn + srow) * (u32)K + (u32)lc * 8;
  }
  const int wdst = w * 512;   // wave's 64-chunk block within a 4096-u16 round
  const int cso0 = ((0 + lk) ^ (lr & 7)) * 8;
  const int cso1 = ((4 + lk) ^ (lr & 7)) * 8;
  int arow[4], brow[2];
#pragma unroll
  for (int f = 0; f < 4; ++f) arow[f] = (wr * 64 + f * 16 + lr) * 64;
#pragma unroll
  for (int f = 0; f < 2; ++f) brow[f] = (wc * 32 + f * 16 + lr) * 64;

  const int NS = K >> 6;
  f32x4 acc[4][2] = {};

#define STG(sl) do {                                                                                  \
    u16* Ad = lds + ((sl) & 1) * 16384;                                                               \
    u16* Bd = Ad + 8192;                                                                              \
    const u32 ko = (u32)(sl) * 64;                                                                    \
    _Pragma("unroll")                                                                                 \
    for (int i = 0; i < 2; ++i) {                                                                     \
      __builtin_amdgcn_global_load_lds(GLBP(A + aofs[i] + ko), LDSP(Ad + i * 4096 + wdst), 16, 0, 0); \
      __builtin_amdgcn_global_load_lds(GLBP(Bt + bofs[i] + ko), LDSP(Bd + i * 4096 + wdst), 16, 0, 0);\
    }                                                                                                 \
  } while (0)
#define RD(afX, bqX, sl, cso) do {                                                                    \
    const u16* As_ = lds + ((sl) & 1) * 16384;                                                        \
    const u16* Bs_ = As_ + 8192;                                                                      \
    _Pragma("unroll")                                                                                 \
    for (int f = 0; f < 4; ++f) afX[f] = *(const bf16x8*)(As_ + arow[f] + (cso));                     \
    _Pragma("unroll")                                                                                 \
    for (int f = 0; f < 2; ++f) bqX[f] = *(const bf16x8*)(Bs_ + brow[f] + (cso));                     \
  } while (0)
#define MM(afX, bqX)                                                                                  \
  _Pragma("unroll") for (int nf = 0; nf < 2; ++nf)                                                    \
  _Pragma("unroll") for (int mf = 0; mf < 4; ++mf)                                                    \
    acc[mf][nf] = __builtin_amdgcn_mfma_f32_16x16x32_bf16(afX[mf], bqX[nf], acc[mf][nf], 0, 0, 0);

  bf16x8 afA[4], bqA[2], afB[4], bqB[2];

  STG(0);
  asm volatile("s_waitcnt vmcnt(0)" ::: "memory");
  __builtin_amdgcn_s_barrier();
  RD(afA, bqA, 0, cso0);
  asm volatile("s_waitcnt lgkmcnt(0)" ::: "memory");
  __builtin_amdgcn_sched_barrier(0);

  for (int s = 0; s < NS; ++s) {
    if (s + 1 < NS) STG(s + 1);
    RD(afB, bqB, s, cso1);
    __builtin_amdgcn_sched_barrier(0);
    __builtin_amdgcn_s_setprio(1);
    MM(afA, bqA);
    __builtin_amdgcn_s_setprio(0);
    asm volatile("s_waitcnt lgkmcnt(0)" ::: "memory");
    __builtin_amdgcn_sched_barrier(0);
    asm volatile("s_waitcnt vmcnt(0)" ::: "memory");
    __builtin_amdgcn_s_barrier();
    if (s + 1 < NS) RD(afA, bqA, s + 1, cso0);
    __builtin_amdgcn_sched_barrier(0);
    __builtin_amdgcn_s_setprio(1);
    MM(afB, bqB);
    __builtin_amdgcn_s_setprio(0);
    asm volatile("s_waitcnt lgkmcnt(0)" ::: "memory");
    __builtin_amdgcn_sched_barrier(0);
  }
#undef STG
#undef RD
#undef MM

  const int obf = ODYN ? (flags[0] ? 0 : 1) : 0;
  (void)Mr;
#pragma unroll
  for (int mf = 0; mf < 4; ++mf) {
#pragma unroll
    for (int nf = 0; nf < 2; ++nf) {
      const int col = tn + wc * 32 + nf * 16 + lr;
      const float bv = bias[col];
#pragma unroll
      for (int j = 0; j < 4; ++j) {
        const int rw = tm + wr * 64 + mf * 16 + lk * 4 + j;
        float vv = acc[mf][nf][j] + bv;
        if (RES) vv += res[(size_t)rw * N + col];
        if (GELU) vv = geluf(vv);
        if (WF) {
          if (ODYN && obf) ((u16*)outF)[(size_t)rw * N + col] = f2b(vv);
          else ((float*)outF)[(size_t)rw * N + col] = vv;
        }
        if (WB) outB[(size_t)rw * N + col] = f2b(vv);
      }
    }
  }
}

// --------------------------------------------------------------- l2 norms
__global__ __launch_bounds__(256) void l2_q(const float* __restrict__ qpre, u16* __restrict__ Q) {
  const int t = threadIdx.x;
  const int g = blockIdx.x * 64 + (t >> 2);
  const int lg = t & 3;
  const int h = g & (NH_ - 1), sb = g >> 4;
  const float* p = qpre + (size_t)sb * H_ + h * D_ + lg * 32;
  float vv[32];
  float ss = 0.f;
#pragma unroll
  for (int i = 0; i < 8; ++i) {
    float4 a = *(const float4*)&p[i * 4];
    vv[i * 4 + 0] = a.x; vv[i * 4 + 1] = a.y; vv[i * 4 + 2] = a.z; vv[i * 4 + 3] = a.w;
    ss += a.x * a.x + a.y * a.y + a.z * a.z + a.w * a.w;
  }
  ss += __shfl_xor(ss, 1); ss += __shfl_xor(ss, 2);
  const float sc = rsqrtf(ss + 1e-12f);
  const int s = sb >> 1, b = sb & 1;
  u16* o = Q + ((size_t)(b * NH_ + h) * S_ + s) * D_ + lg * 32;
#pragma unroll
  for (int i = 0; i < 4; ++i) {
    bf16x8 ov;
#pragma unroll
    for (int j = 0; j < 8; ++j) ov[j] = (short)f2b(vv[i * 8 + j] * sc);
    *(bf16x8*)&o[i * 8] = ov;
  }
}

__global__ __launch_bounds__(256) void l2_kv(const float* __restrict__ kvpre, u16* __restrict__ Kq, u16* __restrict__ Vt) {
  __shared__ u16 vtT[128][72];
  const int t = threadIdx.x;
  const int bid = blockIdx.x;
  const int mt = bid & 31, h = (bid >> 5) & 15, b = bid >> 9;
  const int lm = t >> 2, lg = t & 3;
  const int m = mt * 64 + lm;
  const size_t rowoff = (size_t)(m * B_ + b) * (2 * H_) + h * 256;
  float vv[32];
  { // K half
    const float* p = kvpre + rowoff + lg * 32;
    float ss = 0.f;
#pragma unroll
    for (int i = 0; i < 8; ++i) {
      float4 a = *(const float4*)&p[i * 4];
      vv[i * 4 + 0] = a.x; vv[i * 4 + 1] = a.y; vv[i * 4 + 2] = a.z; vv[i * 4 + 3] = a.w;
      ss += a.x * a.x + a.y * a.y + a.z * a.z + a.w * a.w;
    }
    ss += __shfl_xor(ss, 1); ss += __shfl_xor(ss, 2);
    const float sc = rsqrtf(ss + 1e-12f);
    u16* o = Kq + ((size_t)(b * NH_ + h) * M_ + m) * D_ + lg * 32;
#pragma unroll
    for (int i = 0; i < 4; ++i) {
      bf16x8 ov;
#pragma unroll
      for (int j = 0; j < 8; ++j) ov[j] = (short)f2b(vv[i * 8 + j] * sc);
      *(bf16x8*)&o[i * 8] = ov;
    }
  }
  { // V half -> LDS transposed
    const float* p = kvpre + rowoff + 128 + lg * 32;
    float ss = 0.f;
#pragma unroll
    for (int i = 0; i < 8; ++i) {
      float4 a = *(const float4*)&p[i * 4];
      vv[i * 4 + 0] = a.x; vv[i * 4 + 1] = a.y; vv[i * 4 + 2] = a.z; vv[i * 4 + 3] = a.w;
      ss += a.x * a.x + a.y * a.y + a.z * a.z + a.w * a.w;
    }
    ss += __shfl_xor(ss, 1); ss += __shfl_xor(ss, 2);
    const float sc = rsqrtf(ss + 1e-12f);
#pragma unroll
    for (int i = 0; i < 32; ++i) vtT[lg * 32 + i][lm] = f2b(vv[i] * sc);
  }
  __syncthreads();
  const int d = t >> 1, half = t & 1;
  u16* o = Vt + ((size_t)(b * NH_ + h) * D_ + d) * M_ + mt * 64 + half * 32;
#pragma unroll
  for (int i = 0; i < 4; ++i) {
    bf16x8 ov = *(const bf16x8*)&vtT[d][half * 32 + i * 8];
    *(bf16x8*)&o[i * 8] = ov;
  }
}

// -------------------------------------------------------------- attention
// unchanged (verified; ~130 us)
__global__ __launch_bounds__(256, 3) void attn_k(const u16* __restrict__ Q, const u16* __restrict__ Kq,
                                                 const u16* __restrict__ Vt, const u32* __restrict__ BM32,
                                                 u16* __restrict__ ctx) {
  __shared__ u16 Kl[2][4096];
  __shared__ u16 Vl[2][4096];
  __shared__ u16 Pl[4][16 * 40];
  const int t = threadIdx.x, w = t >> 6, l = t & 63, lr = l & 15, lk = l >> 4;
  const int lin = blockIdx.x;
  const int xcd = lin & 7, idx = lin >> 3;
  const int bh = xcd * 4 + (idx >> 5);
  const int chunk = idx & 31;
  const int b = bh >> 4, h = bh & 15;
  const int srow = chunk * 64 + w * 16;
  const u16* Qb = Q + ((size_t)bh * S_ + srow) * D_;
  bf16x8 qf[4];
#pragma unroll
  for (int kc = 0; kc < 4; ++kc)
    qf[kc] = *(const bf16x8*)&Qb[lr * D_ + kc * 32 + lk * 8];
  f32x4 oacc[8] = {};
  float den[4] = {};
  const u16* Kb = Kq + (size_t)bh * M_ * D_;
  const u16* Vb = Vt + (size_t)bh * D_ * M_;
  const float invn = 0.08838834764831845f;
  u32 ksrc[2], vsrc[2];
#pragma unroll
  for (int i = 0; i < 2; ++i) {
    const int kidx = i * 256 + t;
    const int kr = kidx >> 4, kc_ = (kidx & 15) ^ (kr & 7);
    ksrc[i] = (u32)kr * D_ + (u32)kc_ * 8;
    const int vidx = i * 256 + t;
    const int vd = vidx >> 2, vc = (vidx & 3) ^ ((vd >> 1) & 3);
    vsrc[i] = (u32)vd * M_ + (u32)vc * 8;
  }
  const int wdst = w * 64 * 8;
  u32 mrow[4];
#pragma unroll
  for (int j2 = 0; j2 < 4; ++j2)
    mrow[j2] = ((u32)b * S_ + (u32)(srow + lk * 4 + j2)) * 64u;

#define STG(buf, m0) do {                                                                              \
    _Pragma("unroll")                                                                                  \
    for (int i = 0; i < 2; ++i) {                                                                      \
      __builtin_amdgcn_global_load_lds(GLBP(Kb + (size_t)(m0) * D_ + ksrc[i]),                         \
                                       LDSP(&Kl[buf][i * 2048 + wdst]), 16, 0, 0);                     \
      __builtin_amdgcn_global_load_lds(GLBP(Vb + (size_t)(m0) + vsrc[i]),                              \
                                       LDSP(&Vl[buf][i * 2048 + wdst]), 16, 0, 0);                     \
    }                                                                                                  \
  } while (0)

  STG(0, 0);
  asm volatile("s_waitcnt vmcnt(0)" ::: "memory");
  __builtin_amdgcn_s_barrier();
  int cur = 0;

  for (int t64 = 0; t64 < M_ / 32; ++t64) {
    const int m0 = t64 * 32;
    if (t64 + 1 < M_ / 32) STG(cur ^ 1, m0 + 32);
    u32 mw[4];
#pragma unroll
    for (int j2 = 0; j2 < 4; ++j2) mw[j2] = BM32[mrow[j2] + t64];
    f32x4 sc[2] = {};
#pragma unroll
    for (int mf = 0; mf < 2; ++mf) {
      const int r = mf * 16 + lr;
#pragma unroll
      for (int kc = 0; kc < 4; ++kc) {
        const int cc = ((kc * 4 + lk) ^ (r & 7));
        bf16x8 kfv = *(const bf16x8*)&Kl[cur][r * 128 + cc * 8];
        sc[mf] = __builtin_amdgcn_mfma_f32_16x16x32_bf16(qf[kc], kfv, sc[mf], 0, 0, 0);
      }
    }
#pragma unroll
    for (int j2 = 0; j2 < 4; ++j2) {
      const int rloc = lk * 4 + j2;
#pragma unroll
      for (int mf = 0; mf < 2; ++mf) {
        float p = __expf(sc[mf][j2] * invn);
        p = ((mw[j2] >> (mf * 16 + lr)) & 1u) ? p : 0.0f;
        den[j2] += p;
        Pl[w][rloc * 40 + mf * 16 + lr] = f2b(p);
      }
    }
    asm volatile("s_waitcnt lgkmcnt(0)" ::: "memory");
    __builtin_amdgcn_sched_barrier(0);
    bf16x8 pa = *(const bf16x8*)&Pl[w][lr * 40 + lk * 8];
#pragma unroll
    for (int nf = 0; nf < 8; ++nf) {
      const int d = nf * 16 + lr;
      const int cc = lk ^ ((d >> 1) & 3);
      bf16x8 vfv = *(const bf16x8*)&Vl[cur][d * 32 + cc * 8];
      oacc[nf] = __builtin_amdgcn_mfma_f32_16x16x32_bf16(pa, vfv, oacc[nf], 0, 0, 0);
    }
    asm volatile("s_waitcnt vmcnt(0)" ::: "memory");
    __builtin_amdgcn_s_barrier();
    cur ^= 1;
  }
#undef STG
#pragma unroll
  for (int j2 = 0; j2 < 4; ++j2) {
    float d = den[j2];
    d += __shfl_xor(d, 1); d += __shfl_xor(d, 2); d += __shfl_xor(d, 4); d += __shfl_xor(d, 8);
    den[j2] = 1.0f / fmaxf(d, 1e-20f);
  }
#pragma unroll
  for (int nf = 0; nf < 8; ++nf)
#pragma unroll
    for (int j2 = 0; j2 < 4; ++j2) {
      const int s = srow + lk * 4 + j2;
      const int dd = nf * 16 + lr;
      ctx[((size_t)s * B_ + b) * H_ + h * D_ + dd] = f2b(oacc[nf][j2] * den[j2]);
    }
}

// ------------------------------------------------------------------- host
extern "C" void kernel_launch(void* const* d_in, const int* in_sizes, int n_in,
                              void* d_out, int out_size, void* d_ws, size_t ws_size,
                              hipStream_t stream) {
  (void)in_sizes; (void)n_in; (void)out_size; (void)ws_size;
  char* ws = (char*)d_ws;
  u16* WT     = (u16*)(ws + 0);
  void* MID   = (void*)(ws + 33554432);
  float* XF   = (float*)(ws + 100663296);
  u16* HB     = (u16*)(ws + 134217728);
  u16* MEMB   = (u16*)(ws + 150994944);
  u16* QB     = (u16*)(ws + 167772160);
  u16* KB     = (u16*)(ws + 184549376);
  u16* VTB    = (u16*)(ws + 201326592);
  u64* BMB    = (u64*)(ws + 218103808);
  float* SM   = (float*)(ws + 234881024);
  int* FLAGS  = (int*)(ws + 235044864);

  float* Bias1  = SM + 0;
  float* Bias1o = SM + 8192;
  float* BiasQ  = SM + 10240;
  float* BiasKV = SM + 12288;
  float* BiasD  = SM + 16384;
  float* Bias2  = SM + 18432;
  float* Bias2o = SM + 26624;
  float* G1v = SM + 28672; float* B1v = SM + 30720;
  float* G2v = SM + 32768; float* B2v = SM + 34816;
  float* G3v = SM + 36864; float* B3v = SM + 38912;

  detect_kinds<<<1, 64, 0, stream>>>((const u32*)d_in[0], (const u32*)d_in[2], FLAGS);

  cvt_all<<<160, 256, 0, stream>>>(d_in[10], d_in[12], d_in[14], d_in[16], d_in[18],
                                   d_in[20], d_in[22], d_in[3], d_in[4], d_in[5],
                                   d_in[6], d_in[7], d_in[8], FLAGS, SM);

  mask_bits<<<(B_ * S_ * M_) / 256, 256, 0, stream>>>(d_in[2], FLAGS, BMB);
  cast_in_bf16<<<(MB_ * H_ / 8) / 256, 256, 0, stream>>>(d_in[1], FLAGS, MEMB, MB_ * H_ / 8);

  dim3 blk(256);
  dim3 blk5(512);
  // ---- mlp1  (A/B: gemmra512 on the GELU GEMM)
  layernorm_k<1><<<SB_, blk, 0, stream>>>(d_in[0], FLAGS, G1v, B1v, HB);
  transpose_cast<<<dim3(FF_ / 64, H_ / 64), blk, 0, stream>>>(d_in[9], FLAGS, WT, H_, FF_);
  gemmra512<1, 0, 0, 1, 0><<<dim3(FF_ / 128, SB_ / 128), blk5, 0, stream>>>(HB, WT, Bias1, nullptr, nullptr, (u16*)MID, FLAGS, SB_, FF_, H_);
  transpose_cast<<<dim3(H_ / 64, FF_ / 64), blk, 0, stream>>>(d_in[11], FLAGS, WT, FF_, H_);
  gemmra<0, 0, 1, 0, 0><<<dim3(H_ / 128, SB_ / 128), blk, 0, stream>>>((u16*)MID, WT, Bias1o, nullptr, XF, nullptr, FLAGS, SB_, H_, FF_);

  // ---- memory attention
  layernorm_k<0><<<SB_, blk, 0, stream>>>(XF, FLAGS, G2v, B2v, HB);
  transpose_cast<<<dim3(H_ / 64, H_ / 64), blk, 0, stream>>>(d_in[13], FLAGS, WT, H_, H_);
  gemmra<0, 0, 1, 0, 0><<<dim3(H_ / 128, SB_ / 128), blk, 0, stream>>>(HB, WT, BiasQ, nullptr, MID, nullptr, FLAGS, SB_, H_, H_);
  l2_q<<<(SB_ * NH_) / 64, blk, 0, stream>>>((const float*)MID, QB);
  transpose_cast<<<dim3(2 * H_ / 64, H_ / 64), blk, 0, stream>>>(d_in[15], FLAGS, WT, H_, 2 * H_);
  gemmra<0, 0, 1, 0, 0><<<dim3(2 * H_ / 128, MB_ / 128), blk, 0, stream>>>(MEMB, WT, BiasKV, nullptr, MID, nullptr, FLAGS, MB_, 2 * H_, H_);
  l2_kv<<<B_ * NH_ * (M_ / 64), blk, 0, stream>>>((const float*)MID, KB, VTB);
  attn_k<<<1024, blk, 0, stream>>>(QB, KB, VTB, (const u32*)BMB, MEMB);
  transpose_cast<<<dim3(H_ / 64, H_ / 64), blk, 0, stream>>>(d_in[17], FLAGS, WT, H_, H_);
  gemmra<0, 1, 1, 0, 0><<<dim3(H_ / 128, SB_ / 128), blk, 0, stream>>>(MEMB, WT, BiasD, XF, XF, nullptr, FLAGS, SB_, H_, H_);

  // ---- mlp2  (A/B: gemmra512 on the GELU GEMM)
  layernorm_k<0><<<SB_, blk, 0, stream>>>(XF, FLAGS, G3v, B3v, HB);
  transpose_cast<<<dim3(FF_ / 64, H_ / 64), blk, 0, stream>>>(d_in[19], FLAGS, WT, H_, FF_);
  gemmra512<1, 0, 0, 1, 0><<<dim3(FF_ / 128, SB_ / 128), blk5, 0, stream>>>(HB, WT, Bias2, nullptr, nullptr, (u16*)MID, FLAGS, SB_, FF_, H_);
  transpose_cast<<<dim3(H_ / 64, FF_ / 64), blk, 0, stream>>>(d_in[21], FLAGS, WT, FF_, H_);
  gemmra<0, 1, 1, 0, 1><<<dim3(H_ / 128, SB_ / 128), blk, 0, stream>>>((u16*)MID, WT, Bias2o, XF, d_out, nullptr, FLAGS, SB_, H_, FF_);
}

// Round 14
// 1122.839 us; speedup vs baseline: 1.1209x; 1.0114x over previous
//
#include <hip/hip_runtime.h>
#include <stdint.h>
#include <stddef.h>

typedef __attribute__((ext_vector_type(8))) short bf16x8;
typedef __attribute__((ext_vector_type(4))) float f32x4;
typedef unsigned short u16;
typedef unsigned int u32;
typedef unsigned long long u64;

static constexpr int S_ = 2048, B_ = 2, H_ = 2048, NH_ = 16, D_ = 128, M_ = 2048, FF_ = 8192;
static constexpr int SB_ = S_ * B_;
static constexpr int MB_ = M_ * B_;

__device__ __forceinline__ float b2f(u16 b) {
  union { u32 u; float f; } v; v.u = ((u32)b) << 16; return v.f;
}
__device__ __forceinline__ u16 f2b(float f) {
  union { float f; u32 u; } v; v.f = f;
  u32 u = v.u;
  return (u16)((u + 0x7FFFu + ((u >> 16) & 1u)) >> 16);
}
__device__ __forceinline__ float geluf(float x) {
  float x3 = x * x * x;
  return 0.5f * x * (1.0f + tanhf(0.7978845608028654f * (x + 0.044715f * x3)));
}

#define LDSP(p) (reinterpret_cast<__attribute__((address_space(3))) uint32_t*>(reinterpret_cast<uintptr_t>(p)))
#define GLBP(p) (reinterpret_cast<const __attribute__((address_space(1))) uint32_t*>(reinterpret_cast<uintptr_t>(p)))

// ---------------------------------------------------------------- detectors
__global__ void detect_kinds(const u32* __restrict__ x0, const u32* __restrict__ mask, int* __restrict__ flags) {
  if (threadIdx.x == 0 && blockIdx.x == 0) {
    int cnt = 0;
    for (int i = 0; i < 256; ++i) {
      u32 e = (x0[i] >> 7) & 0xFFu;
      if (e >= 118u && e <= 130u) ++cnt;
    }
    flags[0] = (cnt >= 128) ? 0 : 1;
    int all01 = 1, allf = 1, allb = 1;
    for (int i = 0; i < 256; ++i) {
      u32 v = mask[i];
      if (v > 1u) all01 = 0;
      if (v != 0u && v != 0x3F800000u) allf = 0;
      u32 lo = v & 0xFFFFu, hi = v >> 16;
      if ((lo != 0u && lo != 0x3F80u) || (hi != 0u && hi != 0x3F80u)) allb = 0;
    }
    flags[1] = all01 ? 1 : (allf ? 3 : (allb ? 2 : 0));
  }
}

// mask -> packed bitmask: bit m = 1 iff UNMASKED
__global__ void mask_bits(const void* __restrict__ mraw, const int* __restrict__ flags, u64* __restrict__ bm) {
  int i = blockIdx.x * 256 + threadIdx.x;
  int kind = flags[1];
  int masked;
  if (kind == 1)      masked = ((const int*)mraw)[i] != 0;
  else if (kind == 3) masked = ((const float*)mraw)[i] != 0.0f;
  else if (kind == 2) masked = ((const u16*)mraw)[i] != 0;
  else                masked = ((const unsigned char*)mraw)[i] != 0;
  u64 vote = __ballot(masked == 0);
  if ((threadIdx.x & 63) == 0) bm[i >> 6] = vote;
}

// one launch for all 13 small f32 param conversions
__global__ void cvt_all(const void* s0, const void* s1, const void* s2, const void* s3,
                        const void* s4, const void* s5, const void* s6, const void* s7,
                        const void* s8, const void* s9, const void* s10, const void* s11,
                        const void* s12, const int* __restrict__ flags, float* __restrict__ SM) {
  const int i = blockIdx.x * 256 + threadIdx.x;
  if (i >= 40960) return;
  const void* src; int off;
  if (i < 8192)       { src = s0;  off = 0; }
  else if (i < 10240) { src = s1;  off = 8192; }
  else if (i < 12288) { src = s2;  off = 10240; }
  else if (i < 16384) { src = s3;  off = 12288; }
  else if (i < 18432) { src = s4;  off = 16384; }
  else if (i < 26624) { src = s5;  off = 18432; }
  else if (i < 28672) { src = s6;  off = 26624; }
  else if (i < 30720) { src = s7;  off = 28672; }
  else if (i < 32768) { src = s8;  off = 30720; }
  else if (i < 34816) { src = s9;  off = 32768; }
  else if (i < 36864) { src = s10; off = 34816; }
  else if (i < 38912) { src = s11; off = 36864; }
  else                { src = s12; off = 38912; }
  const int j = i - off;
  SM[i] = flags[0] ? ((const float*)src)[j] : b2f(((const u16*)src)[j]);
}

__global__ void cast_in_bf16(const void* __restrict__ src, const int* __restrict__ flags, u16* __restrict__ dst, int n8) {
  int i = blockIdx.x * 256 + threadIdx.x;
  if (i >= n8) return;
  if (flags[0]) {
    const float4* p = (const float4*)src;
    float4 a = p[i * 2], c = p[i * 2 + 1];
    bf16x8 o;
    o[0] = (short)f2b(a.x); o[1] = (short)f2b(a.y); o[2] = (short)f2b(a.z); o[3] = (short)f2b(a.w);
    o[4] = (short)f2b(c.x); o[5] = (short)f2b(c.y); o[6] = (short)f2b(c.z); o[7] = (short)f2b(c.w);
    *(bf16x8*)&dst[i * 8] = o;
  } else {
    *(bf16x8*)&dst[i * 8] = ((const bf16x8*)src)[i];
  }
}

// ------------------------------------------------------------ transpose+cast
__global__ __launch_bounds__(256) void transpose_cast(const void* __restrict__ in, const int* __restrict__ flags,
                                                      u16* __restrict__ out, int R, int C) {
  __shared__ u16 tile[64][65];
  const int isf = flags[0];
  const int tr = blockIdx.y * 64, tc = blockIdx.x * 64;
  const int tx = threadIdx.x & 63, ty = threadIdx.x >> 6;
  const float* inf = (const float*)in;
  const u16* inb = (const u16*)in;
#pragma unroll
  for (int i = 0; i < 16; ++i) {
    int r = ty * 16 + i;
    size_t idx = (size_t)(tr + r) * C + tc + tx;
    tile[r][tx] = isf ? f2b(inf[idx]) : inb[idx];
  }
  __syncthreads();
#pragma unroll
  for (int i = 0; i < 16; ++i) {
    int c = ty * 16 + i;
    out[(size_t)(tc + c) * R + tr + tx] = tile[tx][c];
  }
}

// ---------------------------------------------------------------- layernorm
template <int EXT>
__global__ __launch_bounds__(256) void layernorm_k(const void* __restrict__ xin, const int* __restrict__ flags,
                                                   const float* __restrict__ g, const float* __restrict__ bta,
                                                   u16* __restrict__ out) {
  const int row = blockIdx.x, t = threadIdx.x;
  float v[8];
  bool bfmode = EXT && (flags[0] == 0);
  if (bfmode) {
    const u16* xr = (const u16*)xin + (size_t)row * H_ + t * 8;
    bf16x8 a = *(const bf16x8*)xr;
#pragma unroll
    for (int j = 0; j < 8; ++j) v[j] = b2f((u16)a[j]);
  } else {
    const float* xr = (const float*)xin + (size_t)row * H_ + t * 8;
    float4 a = *(const float4*)xr, c = *(const float4*)(xr + 4);
    v[0] = a.x; v[1] = a.y; v[2] = a.z; v[3] = a.w;
    v[4] = c.x; v[5] = c.y; v[6] = c.z; v[7] = c.w;
  }
  float s1 = 0.f, s2 = 0.f;
#pragma unroll
  for (int j = 0; j < 8; ++j) { s1 += v[j]; s2 += v[j] * v[j]; }
#pragma unroll
  for (int off = 32; off > 0; off >>= 1) { s1 += __shfl_down(s1, off); s2 += __shfl_down(s2, off); }
  __shared__ float red[8];
  const int w = t >> 6;
  if ((t & 63) == 0) { red[w] = s1; red[4 + w] = s2; }
  __syncthreads();
  s1 = red[0] + red[1] + red[2] + red[3];
  s2 = red[4] + red[5] + red[6] + red[7];
  const float mean = s1 * (1.0f / H_);
  const float rstd = rsqrtf(s2 * (1.0f / H_) - mean * mean + 1e-5f);
  bf16x8 o;
#pragma unroll
  for (int j = 0; j < 8; ++j) {
    float y = (v[j] - mean) * rstd * g[t * 8 + j] + bta[t * 8 + j];
    o[j] = (short)f2b(y);
  }
  *(bf16x8*)(out + (size_t)row * H_ + t * 8) = o;
}

// ------------------------------------------------------------------- GEMM
// gemmra512: the round-13 A/B winner, now used for ALL GEMMs.
// 128x128 tile, 512 thr = 8 waves (2M x 4N, per-wave 64x32 out), BK=64,
// 2-slot double buffer (64KB -> 2 blocks/CU = 16 waves/CU = 4/SIMD),
// register read-ahead, ONE barrier + one vmcnt(0) per slice.  16x16x32 MFMA.
// TLP (m114) fills the per-slice sync bubbles: 208us -> 182us measured.
template <int GELU, int RES, int WF, int WB, int ODYN>
__global__ __launch_bounds__(512, 2) void gemmra512(const u16* __restrict__ A, const u16* __restrict__ Bt,
                                                    const float* __restrict__ bias, const float* __restrict__ res,
                                                    void* __restrict__ outF, u16* __restrict__ outB,
                                                    const int* __restrict__ flags, int Mr, int N, int K) {
  __shared__ u16 lds[32768];   // 64 KiB
  const int t = threadIdx.x;
  const int w = t >> 6, l = t & 63, lr = l & 15, lk = l >> 4;
  const int wr = w >> 2, wc = w & 3;
  const int gx = gridDim.x, gy = gridDim.y;
  const int orig = blockIdx.y * gx + blockIdx.x;
  const int nwg = gx * gy, per = nwg >> 3;
  int tm, tn;
  if ((gx & 7) == 0 && (per & 7) == 0) {
    const int xcd = orig & 7, p = orig >> 3;
    const int ncx = gx >> 3, cy = per >> 3;
    const int ccol = xcd % ncx, crow = xcd / ncx;
    const int px = p & 7, py = p >> 3;
    tn = (ccol * 8 + px) * 128;
    tm = (crow * cy + py) * 128;
  } else {
    tn = (orig % gx) * 128;
    tm = (orig / gx) * 128;
  }
  // staging: 1024 chunks per operand per slice, 512 threads -> 2 rounds
  u32 aofs[2], bofs[2];
#pragma unroll
  for (int i = 0; i < 2; ++i) {
    const int idx = i * 512 + t;
    const int srow = idx >> 3, sc = idx & 7;
    const int lc = sc ^ (srow & 7);
    aofs[i] = (u32)(tm + srow) * (u32)K + (u32)lc * 8;
    bofs[i] = (u32)(tn + srow) * (u32)K + (u32)lc * 8;
  }
  const int wdst = w * 512;   // wave's 64-chunk block within a 4096-u16 round
  const int cso0 = ((0 + lk) ^ (lr & 7)) * 8;
  const int cso1 = ((4 + lk) ^ (lr & 7)) * 8;
  int arow[4], brow[2];
#pragma unroll
  for (int f = 0; f < 4; ++f) arow[f] = (wr * 64 + f * 16 + lr) * 64;
#pragma unroll
  for (int f = 0; f < 2; ++f) brow[f] = (wc * 32 + f * 16 + lr) * 64;

  const int NS = K >> 6;
  f32x4 acc[4][2] = {};

#define STG(sl) do {                                                                                  \
    u16* Ad = lds + ((sl) & 1) * 16384;                                                               \
    u16* Bd = Ad + 8192;                                                                              \
    const u32 ko = (u32)(sl) * 64;                                                                    \
    _Pragma("unroll")                                                                                 \
    for (int i = 0; i < 2; ++i) {                                                                     \
      __builtin_amdgcn_global_load_lds(GLBP(A + aofs[i] + ko), LDSP(Ad + i * 4096 + wdst), 16, 0, 0); \
      __builtin_amdgcn_global_load_lds(GLBP(Bt + bofs[i] + ko), LDSP(Bd + i * 4096 + wdst), 16, 0, 0);\
    }                                                                                                 \
  } while (0)
#define RD(afX, bqX, sl, cso) do {                                                                    \
    const u16* As_ = lds + ((sl) & 1) * 16384;                                                        \
    const u16* Bs_ = As_ + 8192;                                                                      \
    _Pragma("unroll")                                                                                 \
    for (int f = 0; f < 4; ++f) afX[f] = *(const bf16x8*)(As_ + arow[f] + (cso));                     \
    _Pragma("unroll")                                                                                 \
    for (int f = 0; f < 2; ++f) bqX[f] = *(const bf16x8*)(Bs_ + brow[f] + (cso));                     \
  } while (0)
#define MM(afX, bqX)                                                                                  \
  _Pragma("unroll") for (int nf = 0; nf < 2; ++nf)                                                    \
  _Pragma("unroll") for (int mf = 0; mf < 4; ++mf)                                                    \
    acc[mf][nf] = __builtin_amdgcn_mfma_f32_16x16x32_bf16(afX[mf], bqX[nf], acc[mf][nf], 0, 0, 0);

  bf16x8 afA[4], bqA[2], afB[4], bqB[2];

  STG(0);
  asm volatile("s_waitcnt vmcnt(0)" ::: "memory");
  __builtin_amdgcn_s_barrier();
  RD(afA, bqA, 0, cso0);
  asm volatile("s_waitcnt lgkmcnt(0)" ::: "memory");
  __builtin_amdgcn_sched_barrier(0);

  for (int s = 0; s < NS; ++s) {
    if (s + 1 < NS) STG(s + 1);
    RD(afB, bqB, s, cso1);
    __builtin_amdgcn_sched_barrier(0);
    __builtin_amdgcn_s_setprio(1);
    MM(afA, bqA);
    __builtin_amdgcn_s_setprio(0);
    asm volatile("s_waitcnt lgkmcnt(0)" ::: "memory");
    __builtin_amdgcn_sched_barrier(0);
    asm volatile("s_waitcnt vmcnt(0)" ::: "memory");
    __builtin_amdgcn_s_barrier();
    if (s + 1 < NS) RD(afA, bqA, s + 1, cso0);
    __builtin_amdgcn_sched_barrier(0);
    __builtin_amdgcn_s_setprio(1);
    MM(afB, bqB);
    __builtin_amdgcn_s_setprio(0);
    asm volatile("s_waitcnt lgkmcnt(0)" ::: "memory");
    __builtin_amdgcn_sched_barrier(0);
  }
#undef STG
#undef RD
#undef MM

  const int obf = ODYN ? (flags[0] ? 0 : 1) : 0;
  (void)Mr;
#pragma unroll
  for (int mf = 0; mf < 4; ++mf) {
#pragma unroll
    for (int nf = 0; nf < 2; ++nf) {
      const int col = tn + wc * 32 + nf * 16 + lr;
      const float bv = bias[col];
#pragma unroll
      for (int j = 0; j < 4; ++j) {
        const int rw = tm + wr * 64 + mf * 16 + lk * 4 + j;
        float vv = acc[mf][nf][j] + bv;
        if (RES) vv += res[(size_t)rw * N + col];
        if (GELU) vv = geluf(vv);
        if (WF) {
          if (ODYN && obf) ((u16*)outF)[(size_t)rw * N + col] = f2b(vv);
          else ((float*)outF)[(size_t)rw * N + col] = vv;
        }
        if (WB) outB[(size_t)rw * N + col] = f2b(vv);
      }
    }
  }
}

// --------------------------------------------------------------- l2 norms
__global__ __launch_bounds__(256) void l2_q(const float* __restrict__ qpre, u16* __restrict__ Q) {
  const int t = threadIdx.x;
  const int g = blockIdx.x * 64 + (t >> 2);
  const int lg = t & 3;
  const int h = g & (NH_ - 1), sb = g >> 4;
  const float* p = qpre + (size_t)sb * H_ + h * D_ + lg * 32;
  float vv[32];
  float ss = 0.f;
#pragma unroll
  for (int i = 0; i < 8; ++i) {
    float4 a = *(const float4*)&p[i * 4];
    vv[i * 4 + 0] = a.x; vv[i * 4 + 1] = a.y; vv[i * 4 + 2] = a.z; vv[i * 4 + 3] = a.w;
    ss += a.x * a.x + a.y * a.y + a.z * a.z + a.w * a.w;
  }
  ss += __shfl_xor(ss, 1); ss += __shfl_xor(ss, 2);
  const float sc = rsqrtf(ss + 1e-12f);
  const int s = sb >> 1, b = sb & 1;
  u16* o = Q + ((size_t)(b * NH_ + h) * S_ + s) * D_ + lg * 32;
#pragma unroll
  for (int i = 0; i < 4; ++i) {
    bf16x8 ov;
#pragma unroll
    for (int j = 0; j < 8; ++j) ov[j] = (short)f2b(vv[i * 8 + j] * sc);
    *(bf16x8*)&o[i * 8] = ov;
  }
}

__global__ __launch_bounds__(256) void l2_kv(const float* __restrict__ kvpre, u16* __restrict__ Kq, u16* __restrict__ Vt) {
  __shared__ u16 vtT[128][72];
  const int t = threadIdx.x;
  const int bid = blockIdx.x;
  const int mt = bid & 31, h = (bid >> 5) & 15, b = bid >> 9;
  const int lm = t >> 2, lg = t & 3;
  const int m = mt * 64 + lm;
  const size_t rowoff = (size_t)(m * B_ + b) * (2 * H_) + h * 256;
  float vv[32];
  { // K half
    const float* p = kvpre + rowoff + lg * 32;
    float ss = 0.f;
#pragma unroll
    for (int i = 0; i < 8; ++i) {
      float4 a = *(const float4*)&p[i * 4];
      vv[i * 4 + 0] = a.x; vv[i * 4 + 1] = a.y; vv[i * 4 + 2] = a.z; vv[i * 4 + 3] = a.w;
      ss += a.x * a.x + a.y * a.y + a.z * a.z + a.w * a.w;
    }
    ss += __shfl_xor(ss, 1); ss += __shfl_xor(ss, 2);
    const float sc = rsqrtf(ss + 1e-12f);
    u16* o = Kq + ((size_t)(b * NH_ + h) * M_ + m) * D_ + lg * 32;
#pragma unroll
    for (int i = 0; i < 4; ++i) {
      bf16x8 ov;
#pragma unroll
      for (int j = 0; j < 8; ++j) ov[j] = (short)f2b(vv[i * 8 + j] * sc);
      *(bf16x8*)&o[i * 8] = ov;
    }
  }
  { // V half -> LDS transposed
    const float* p = kvpre + rowoff + 128 + lg * 32;
    float ss = 0.f;
#pragma unroll
    for (int i = 0; i < 8; ++i) {
      float4 a = *(const float4*)&p[i * 4];
      vv[i * 4 + 0] = a.x; vv[i * 4 + 1] = a.y; vv[i * 4 + 2] = a.z; vv[i * 4 + 3] = a.w;
      ss += a.x * a.x + a.y * a.y + a.z * a.z + a.w * a.w;
    }
    ss += __shfl_xor(ss, 1); ss += __shfl_xor(ss, 2);
    const float sc = rsqrtf(ss + 1e-12f);
#pragma unroll
    for (int i = 0; i < 32; ++i) vtT[lg * 32 + i][lm] = f2b(vv[i] * sc);
  }
  __syncthreads();
  const int d = t >> 1, half = t & 1;
  u16* o = Vt + ((size_t)(b * NH_ + h) * D_ + d) * M_ + mt * 64 + half * 32;
#pragma unroll
  for (int i = 0; i < 4; ++i) {
    bf16x8 ov = *(const bf16x8*)&vtT[d][half * 32 + i * 8];
    *(bf16x8*)&o[i * 8] = ov;
  }
}

// -------------------------------------------------------------- attention
// unchanged (verified; ~130 us)
__global__ __launch_bounds__(256, 3) void attn_k(const u16* __restrict__ Q, const u16* __restrict__ Kq,
                                                 const u16* __restrict__ Vt, const u32* __restrict__ BM32,
                                                 u16* __restrict__ ctx) {
  __shared__ u16 Kl[2][4096];
  __shared__ u16 Vl[2][4096];
  __shared__ u16 Pl[4][16 * 40];
  const int t = threadIdx.x, w = t >> 6, l = t & 63, lr = l & 15, lk = l >> 4;
  const int lin = blockIdx.x;
  const int xcd = lin & 7, idx = lin >> 3;
  const int bh = xcd * 4 + (idx >> 5);
  const int chunk = idx & 31;
  const int b = bh >> 4, h = bh & 15;
  const int srow = chunk * 64 + w * 16;
  const u16* Qb = Q + ((size_t)bh * S_ + srow) * D_;
  bf16x8 qf[4];
#pragma unroll
  for (int kc = 0; kc < 4; ++kc)
    qf[kc] = *(const bf16x8*)&Qb[lr * D_ + kc * 32 + lk * 8];
  f32x4 oacc[8] = {};
  float den[4] = {};
  const u16* Kb = Kq + (size_t)bh * M_ * D_;
  const u16* Vb = Vt + (size_t)bh * D_ * M_;
  const float invn = 0.08838834764831845f;
  u32 ksrc[2], vsrc[2];
#pragma unroll
  for (int i = 0; i < 2; ++i) {
    const int kidx = i * 256 + t;
    const int kr = kidx >> 4, kc_ = (kidx & 15) ^ (kr & 7);
    ksrc[i] = (u32)kr * D_ + (u32)kc_ * 8;
    const int vidx = i * 256 + t;
    const int vd = vidx >> 2, vc = (vidx & 3) ^ ((vd >> 1) & 3);
    vsrc[i] = (u32)vd * M_ + (u32)vc * 8;
  }
  const int wdst = w * 64 * 8;
  u32 mrow[4];
#pragma unroll
  for (int j2 = 0; j2 < 4; ++j2)
    mrow[j2] = ((u32)b * S_ + (u32)(srow + lk * 4 + j2)) * 64u;

#define STG(buf, m0) do {                                                                              \
    _Pragma("unroll")                                                                                  \
    for (int i = 0; i < 2; ++i) {                                                                      \
      __builtin_amdgcn_global_load_lds(GLBP(Kb + (size_t)(m0) * D_ + ksrc[i]),                         \
                                       LDSP(&Kl[buf][i * 2048 + wdst]), 16, 0, 0);                     \
      __builtin_amdgcn_global_load_lds(GLBP(Vb + (size_t)(m0) + vsrc[i]),                              \
                                       LDSP(&Vl[buf][i * 2048 + wdst]), 16, 0, 0);                     \
    }                                                                                                  \
  } while (0)

  STG(0, 0);
  asm volatile("s_waitcnt vmcnt(0)" ::: "memory");
  __builtin_amdgcn_s_barrier();
  int cur = 0;

  for (int t64 = 0; t64 < M_ / 32; ++t64) {
    const int m0 = t64 * 32;
    if (t64 + 1 < M_ / 32) STG(cur ^ 1, m0 + 32);
    u32 mw[4];
#pragma unroll
    for (int j2 = 0; j2 < 4; ++j2) mw[j2] = BM32[mrow[j2] + t64];
    f32x4 sc[2] = {};
#pragma unroll
    for (int mf = 0; mf < 2; ++mf) {
      const int r = mf * 16 + lr;
#pragma unroll
      for (int kc = 0; kc < 4; ++kc) {
        const int cc = ((kc * 4 + lk) ^ (r & 7));
        bf16x8 kfv = *(const bf16x8*)&Kl[cur][r * 128 + cc * 8];
        sc[mf] = __builtin_amdgcn_mfma_f32_16x16x32_bf16(qf[kc], kfv, sc[mf], 0, 0, 0);
      }
    }
#pragma unroll
    for (int j2 = 0; j2 < 4; ++j2) {
      const int rloc = lk * 4 + j2;
#pragma unroll
      for (int mf = 0; mf < 2; ++mf) {
        float p = __expf(sc[mf][j2] * invn);
        p = ((mw[j2] >> (mf * 16 + lr)) & 1u) ? p : 0.0f;
        den[j2] += p;
        Pl[w][rloc * 40 + mf * 16 + lr] = f2b(p);
      }
    }
    asm volatile("s_waitcnt lgkmcnt(0)" ::: "memory");
    __builtin_amdgcn_sched_barrier(0);
    bf16x8 pa = *(const bf16x8*)&Pl[w][lr * 40 + lk * 8];
#pragma unroll
    for (int nf = 0; nf < 8; ++nf) {
      const int d = nf * 16 + lr;
      const int cc = lk ^ ((d >> 1) & 3);
      bf16x8 vfv = *(const bf16x8*)&Vl[cur][d * 32 + cc * 8];
      oacc[nf] = __builtin_amdgcn_mfma_f32_16x16x32_bf16(pa, vfv, oacc[nf], 0, 0, 0);
    }
    asm volatile("s_waitcnt vmcnt(0)" ::: "memory");
    __builtin_amdgcn_s_barrier();
    cur ^= 1;
  }
#undef STG
#pragma unroll
  for (int j2 = 0; j2 < 4; ++j2) {
    float d = den[j2];
    d += __shfl_xor(d, 1); d += __shfl_xor(d, 2); d += __shfl_xor(d, 4); d += __shfl_xor(d, 8);
    den[j2] = 1.0f / fmaxf(d, 1e-20f);
  }
#pragma unroll
  for (int nf = 0; nf < 8; ++nf)
#pragma unroll
    for (int j2 = 0; j2 < 4; ++j2) {
      const int s = srow + lk * 4 + j2;
      const int dd = nf * 16 + lr;
      ctx[((size_t)s * B_ + b) * H_ + h * D_ + dd] = f2b(oacc[nf][j2] * den[j2]);
    }
}

// ------------------------------------------------------------------- host
extern "C" void kernel_launch(void* const* d_in, const int* in_sizes, int n_in,
                              void* d_out, int out_size, void* d_ws, size_t ws_size,
                              hipStream_t stream) {
  (void)in_sizes; (void)n_in; (void)out_size; (void)ws_size;
  char* ws = (char*)d_ws;
  u16* WT     = (u16*)(ws + 0);
  void* MID   = (void*)(ws + 33554432);
  float* XF   = (float*)(ws + 100663296);
  u16* HB     = (u16*)(ws + 134217728);
  u16* MEMB   = (u16*)(ws + 150994944);
  u16* QB     = (u16*)(ws + 167772160);
  u16* KB     = (u16*)(ws + 184549376);
  u16* VTB    = (u16*)(ws + 201326592);
  u64* BMB    = (u64*)(ws + 218103808);
  float* SM   = (float*)(ws + 234881024);
  int* FLAGS  = (int*)(ws + 235044864);

  float* Bias1  = SM + 0;
  float* Bias1o = SM + 8192;
  float* BiasQ  = SM + 10240;
  float* BiasKV = SM + 12288;
  float* BiasD  = SM + 16384;
  float* Bias2  = SM + 18432;
  float* Bias2o = SM + 26624;
  float* G1v = SM + 28672; float* B1v = SM + 30720;
  float* G2v = SM + 32768; float* B2v = SM + 34816;
  float* G3v = SM + 36864; float* B3v = SM + 38912;

  detect_kinds<<<1, 64, 0, stream>>>((const u32*)d_in[0], (const u32*)d_in[2], FLAGS);

  cvt_all<<<160, 256, 0, stream>>>(d_in[10], d_in[12], d_in[14], d_in[16], d_in[18],
                                   d_in[20], d_in[22], d_in[3], d_in[4], d_in[5],
                                   d_in[6], d_in[7], d_in[8], FLAGS, SM);

  mask_bits<<<(B_ * S_ * M_) / 256, 256, 0, stream>>>(d_in[2], FLAGS, BMB);
  cast_in_bf16<<<(MB_ * H_ / 8) / 256, 256, 0, stream>>>(d_in[1], FLAGS, MEMB, MB_ * H_ / 8);

  dim3 blk(256);
  dim3 blk5(512);
  // ---- mlp1
  layernorm_k<1><<<SB_, blk, 0, stream>>>(d_in[0], FLAGS, G1v, B1v, HB);
  transpose_cast<<<dim3(FF_ / 64, H_ / 64), blk, 0, stream>>>(d_in[9], FLAGS, WT, H_, FF_);
  gemmra512<1, 0, 0, 1, 0><<<dim3(FF_ / 128, SB_ / 128), blk5, 0, stream>>>(HB, WT, Bias1, nullptr, nullptr, (u16*)MID, FLAGS, SB_, FF_, H_);
  transpose_cast<<<dim3(H_ / 64, FF_ / 64), blk, 0, stream>>>(d_in[11], FLAGS, WT, FF_, H_);
  gemmra512<0, 0, 1, 0, 0><<<dim3(H_ / 128, SB_ / 128), blk5, 0, stream>>>((u16*)MID, WT, Bias1o, nullptr, XF, nullptr, FLAGS, SB_, H_, FF_);

  // ---- memory attention
  layernorm_k<0><<<SB_, blk, 0, stream>>>(XF, FLAGS, G2v, B2v, HB);
  transpose_cast<<<dim3(H_ / 64, H_ / 64), blk, 0, stream>>>(d_in[13], FLAGS, WT, H_, H_);
  gemmra512<0, 0, 1, 0, 0><<<dim3(H_ / 128, SB_ / 128), blk5, 0, stream>>>(HB, WT, BiasQ, nullptr, MID, nullptr, FLAGS, SB_, H_, H_);
  l2_q<<<(SB_ * NH_) / 64, blk, 0, stream>>>((const float*)MID, QB);
  transpose_cast<<<dim3(2 * H_ / 64, H_ / 64), blk, 0, stream>>>(d_in[15], FLAGS, WT, H_, 2 * H_);
  gemmra512<0, 0, 1, 0, 0><<<dim3(2 * H_ / 128, MB_ / 128), blk5, 0, stream>>>(MEMB, WT, BiasKV, nullptr, MID, nullptr, FLAGS, MB_, 2 * H_, H_);
  l2_kv<<<B_ * NH_ * (M_ / 64), blk, 0, stream>>>((const float*)MID, KB, VTB);
  attn_k<<<1024, blk, 0, stream>>>(QB, KB, VTB, (const u32*)BMB, MEMB);
  transpose_cast<<<dim3(H_ / 64, H_ / 64), blk, 0, stream>>>(d_in[17], FLAGS, WT, H_, H_);
  gemmra512<0, 1, 1, 0, 0><<<dim3(H_ / 128, SB_ / 128), blk5, 0, stream>>>(MEMB, WT, BiasD, XF, XF, nullptr, FLAGS, SB_, H_, H_);

  // ---- mlp2
  layernorm_k<0><<<SB_, blk, 0, stream>>>(XF, FLAGS, G3v, B3v, HB);
  transpose_cast<<<dim3(FF_ / 64, H_ / 64), blk, 0, stream>>>(d_in[19], FLAGS, WT, H_, FF_);
  gemmra512<1, 0, 0, 1, 0><<<dim3(FF_ / 128, SB_ / 128), blk5, 0, stream>>>(HB, WT, Bias2, nullptr, nullptr, (u16*)MID, FLAGS, SB_, FF_, H_);
  transpose_cast<<<dim3(H_ / 64, FF_ / 64), blk, 0, stream>>>(d_in[21], FLAGS, WT, FF_, H_);
  gemmra512<0, 1, 1, 0, 1><<<dim3(H_ / 128, SB_ / 128), blk5, 0, stream>>>((u16*)MID, WT, Bias2o, XF, d_out, nullptr, FLAGS, SB_, H_, FF_);
}

// Round 15
// 1092.164 us; speedup vs baseline: 1.1524x; 1.0281x over previous
//
#include <hip/hip_runtime.h>
#include <stdint.h>
#include <stddef.h>

typedef __attribute__((ext_vector_type(8))) short bf16x8;
typedef __attribute__((ext_vector_type(4))) float f32x4;
typedef unsigned short u16;
typedef unsigned int u32;
typedef unsigned long long u64;

static constexpr int S_ = 2048, B_ = 2, H_ = 2048, NH_ = 16, D_ = 128, M_ = 2048, FF_ = 8192;
static constexpr int SB_ = S_ * B_;
static constexpr int MB_ = M_ * B_;

__device__ __forceinline__ float b2f(u16 b) {
  union { u32 u; float f; } v; v.u = ((u32)b) << 16; return v.f;
}
__device__ __forceinline__ u16 f2b(float f) {
  union { float f; u32 u; } v; v.f = f;
  u32 u = v.u;
  return (u16)((u + 0x7FFFu + ((u >> 16) & 1u)) >> 16);
}
__device__ __forceinline__ float geluf(float x) {
  float x3 = x * x * x;
  return 0.5f * x * (1.0f + tanhf(0.7978845608028654f * (x + 0.044715f * x3)));
}

#define LDSP(p) (reinterpret_cast<__attribute__((address_space(3))) uint32_t*>(reinterpret_cast<uintptr_t>(p)))
#define GLBP(p) (reinterpret_cast<const __attribute__((address_space(1))) uint32_t*>(reinterpret_cast<uintptr_t>(p)))

// ---------------------------------------------------------------- detectors
__global__ void detect_kinds(const u32* __restrict__ x0, const u32* __restrict__ mask, int* __restrict__ flags) {
  if (threadIdx.x == 0 && blockIdx.x == 0) {
    int cnt = 0;
    for (int i = 0; i < 256; ++i) {
      u32 e = (x0[i] >> 7) & 0xFFu;
      if (e >= 118u && e <= 130u) ++cnt;
    }
    flags[0] = (cnt >= 128) ? 0 : 1;
    int all01 = 1, allf = 1, allb = 1;
    for (int i = 0; i < 256; ++i) {
      u32 v = mask[i];
      if (v > 1u) all01 = 0;
      if (v != 0u && v != 0x3F800000u) allf = 0;
      u32 lo = v & 0xFFFFu, hi = v >> 16;
      if ((lo != 0u && lo != 0x3F80u) || (hi != 0u && hi != 0x3F80u)) allb = 0;
    }
    flags[1] = all01 ? 1 : (allf ? 3 : (allb ? 2 : 0));
  }
}

// mask -> packed bitmask: bit m = 1 iff UNMASKED
__global__ void mask_bits(const void* __restrict__ mraw, const int* __restrict__ flags, u64* __restrict__ bm) {
  int i = blockIdx.x * 256 + threadIdx.x;
  int kind = flags[1];
  int masked;
  if (kind == 1)      masked = ((const int*)mraw)[i] != 0;
  else if (kind == 3) masked = ((const float*)mraw)[i] != 0.0f;
  else if (kind == 2) masked = ((const u16*)mraw)[i] != 0;
  else                masked = ((const unsigned char*)mraw)[i] != 0;
  u64 vote = __ballot(masked == 0);
  if ((threadIdx.x & 63) == 0) bm[i >> 6] = vote;
}

// one launch for all 13 small f32 param conversions
__global__ void cvt_all(const void* s0, const void* s1, const void* s2, const void* s3,
                        const void* s4, const void* s5, const void* s6, const void* s7,
                        const void* s8, const void* s9, const void* s10, const void* s11,
                        const void* s12, const int* __restrict__ flags, float* __restrict__ SM) {
  const int i = blockIdx.x * 256 + threadIdx.x;
  if (i >= 40960) return;
  const void* src; int off;
  if (i < 8192)       { src = s0;  off = 0; }
  else if (i < 10240) { src = s1;  off = 8192; }
  else if (i < 12288) { src = s2;  off = 10240; }
  else if (i < 16384) { src = s3;  off = 12288; }
  else if (i < 18432) { src = s4;  off = 16384; }
  else if (i < 26624) { src = s5;  off = 18432; }
  else if (i < 28672) { src = s6;  off = 26624; }
  else if (i < 30720) { src = s7;  off = 28672; }
  else if (i < 32768) { src = s8;  off = 30720; }
  else if (i < 34816) { src = s9;  off = 32768; }
  else if (i < 36864) { src = s10; off = 34816; }
  else if (i < 38912) { src = s11; off = 36864; }
  else                { src = s12; off = 38912; }
  const int j = i - off;
  SM[i] = flags[0] ? ((const float*)src)[j] : b2f(((const u16*)src)[j]);
}

__global__ void cast_in_bf16(const void* __restrict__ src, const int* __restrict__ flags, u16* __restrict__ dst, int n8) {
  int i = blockIdx.x * 256 + threadIdx.x;
  if (i >= n8) return;
  if (flags[0]) {
    const float4* p = (const float4*)src;
    float4 a = p[i * 2], c = p[i * 2 + 1];
    bf16x8 o;
    o[0] = (short)f2b(a.x); o[1] = (short)f2b(a.y); o[2] = (short)f2b(a.z); o[3] = (short)f2b(a.w);
    o[4] = (short)f2b(c.x); o[5] = (short)f2b(c.y); o[6] = (short)f2b(c.z); o[7] = (short)f2b(c.w);
    *(bf16x8*)&dst[i * 8] = o;
  } else {
    *(bf16x8*)&dst[i * 8] = ((const bf16x8*)src)[i];
  }
}

// ------------------------------------------------------------ transpose+cast
__global__ __launch_bounds__(256) void transpose_cast(const void* __restrict__ in, const int* __restrict__ flags,
                                                      u16* __restrict__ out, int R, int C) {
  __shared__ u16 tile[64][65];
  const int isf = flags[0];
  const int tr = blockIdx.y * 64, tc = blockIdx.x * 64;
  const int tx = threadIdx.x & 63, ty = threadIdx.x >> 6;
  const float* inf = (const float*)in;
  const u16* inb = (const u16*)in;
#pragma unroll
  for (int i = 0; i < 16; ++i) {
    int r = ty * 16 + i;
    size_t idx = (size_t)(tr + r) * C + tc + tx;
    tile[r][tx] = isf ? f2b(inf[idx]) : inb[idx];
  }
  __syncthreads();
#pragma unroll
  for (int i = 0; i < 16; ++i) {
    int c = ty * 16 + i;
    out[(size_t)(tc + c) * R + tr + tx] = tile[tx][c];
  }
}

// ---------------------------------------------------------------- layernorm
template <int EXT>
__global__ __launch_bounds__(256) void layernorm_k(const void* __restrict__ xin, const int* __restrict__ flags,
                                                   const float* __restrict__ g, const float* __restrict__ bta,
                                                   u16* __restrict__ out) {
  const int row = blockIdx.x, t = threadIdx.x;
  float v[8];
  bool bfmode = EXT && (flags[0] == 0);
  if (bfmode) {
    const u16* xr = (const u16*)xin + (size_t)row * H_ + t * 8;
    bf16x8 a = *(const bf16x8*)xr;
#pragma unroll
    for (int j = 0; j < 8; ++j) v[j] = b2f((u16)a[j]);
  } else {
    const float* xr = (const float*)xin + (size_t)row * H_ + t * 8;
    float4 a = *(const float4*)xr, c = *(const float4*)(xr + 4);
    v[0] = a.x; v[1] = a.y; v[2] = a.z; v[3] = a.w;
    v[4] = c.x; v[5] = c.y; v[6] = c.z; v[7] = c.w;
  }
  float s1 = 0.f, s2 = 0.f;
#pragma unroll
  for (int j = 0; j < 8; ++j) { s1 += v[j]; s2 += v[j] * v[j]; }
#pragma unroll
  for (int off = 32; off > 0; off >>= 1) { s1 += __shfl_down(s1, off); s2 += __shfl_down(s2, off); }
  __shared__ float red[8];
  const int w = t >> 6;
  if ((t & 63) == 0) { red[w] = s1; red[4 + w] = s2; }
  __syncthreads();
  s1 = red[0] + red[1] + red[2] + red[3];
  s2 = red[4] + red[5] + red[6] + red[7];
  const float mean = s1 * (1.0f / H_);
  const float rstd = rsqrtf(s2 * (1.0f / H_) - mean * mean + 1e-5f);
  bf16x8 o;
#pragma unroll
  for (int j = 0; j < 8; ++j) {
    float y = (v[j] - mean) * rstd * g[t * 8 + j] + bta[t * 8 + j];
    o[j] = (short)f2b(y);
  }
  *(bf16x8*)(out + (size_t)row * H_ + t * 8) = o;
}

// ------------------------------------------------------------------- GEMM
// gemmra512 (round-13 winner) + fused l2-norm epilogues.
// 128x128 tile, 512 thr = 8 waves (2M x 4N, 64x32/wave), BK=64, 2-slot
// double buffer (64KB -> 2 blocks/CU = 4 waves/SIMD), register read-ahead,
// ONE barrier + one vmcnt(0) per slice, 16x16x32 MFMA.
// EPI=0: normal bias/res/gelu epilogue (WF/WB paths).
// EPI=1: Q l2-norm: tile N=128 == head D -> per-row l2 within block;
//        writes QB [B][NH][S][D] bf16 (outB).
// EPI=2: KV l2-norm: tile is a K-slice or V-slice of one head;
//        K -> KB [B][NH][M][D] (outB); V -> LDS-transpose -> VTB
//        [B][NH][D][M] (outF).
template <int GELU, int RES, int WF, int WB, int ODYN, int EPI>
__global__ __launch_bounds__(512, 2) void gemmra512(const u16* __restrict__ A, const u16* __restrict__ Bt,
                                                    const float* __restrict__ bias, const float* __restrict__ res,
                                                    void* __restrict__ outF, u16* __restrict__ outB,
                                                    const int* __restrict__ flags, int Mr, int N, int K) {
  __shared__ u16 lds[32768];   // 64 KiB
  const int t = threadIdx.x;
  const int w = t >> 6, l = t & 63, lr = l & 15, lk = l >> 4;
  const int wr = w >> 2, wc = w & 3;
  const int gx = gridDim.x, gy = gridDim.y;
  const int orig = blockIdx.y * gx + blockIdx.x;
  const int nwg = gx * gy, per = nwg >> 3;
  int tm, tn;
  if ((gx & 7) == 0 && (per & 7) == 0) {
    const int xcd = orig & 7, p = orig >> 3;
    const int ncx = gx >> 3, cy = per >> 3;
    const int ccol = xcd % ncx, crow = xcd / ncx;
    const int px = p & 7, py = p >> 3;
    tn = (ccol * 8 + px) * 128;
    tm = (crow * cy + py) * 128;
  } else {
    tn = (orig % gx) * 128;
    tm = (orig / gx) * 128;
  }
  u32 aofs[2], bofs[2];
#pragma unroll
  for (int i = 0; i < 2; ++i) {
    const int idx = i * 512 + t;
    const int srow = idx >> 3, sc = idx & 7;
    const int lc = sc ^ (srow & 7);
    aofs[i] = (u32)(tm + srow) * (u32)K + (u32)lc * 8;
    bofs[i] = (u32)(tn + srow) * (u32)K + (u32)lc * 8;
  }
  const int wdst = w * 512;
  const int cso0 = ((0 + lk) ^ (lr & 7)) * 8;
  const int cso1 = ((4 + lk) ^ (lr & 7)) * 8;
  int arow[4], brow[2];
#pragma unroll
  for (int f = 0; f < 4; ++f) arow[f] = (wr * 64 + f * 16 + lr) * 64;
#pragma unroll
  for (int f = 0; f < 2; ++f) brow[f] = (wc * 32 + f * 16 + lr) * 64;

  const int NS = K >> 6;
  f32x4 acc[4][2] = {};

#define STG(sl) do {                                                                                  \
    u16* Ad = lds + ((sl) & 1) * 16384;                                                               \
    u16* Bd = Ad + 8192;                                                                              \
    const u32 ko = (u32)(sl) * 64;                                                                    \
    _Pragma("unroll")                                                                                 \
    for (int i = 0; i < 2; ++i) {                                                                     \
      __builtin_amdgcn_global_load_lds(GLBP(A + aofs[i] + ko), LDSP(Ad + i * 4096 + wdst), 16, 0, 0); \
      __builtin_amdgcn_global_load_lds(GLBP(Bt + bofs[i] + ko), LDSP(Bd + i * 4096 + wdst), 16, 0, 0);\
    }                                                                                                 \
  } while (0)
#define RD(afX, bqX, sl, cso) do {                                                                    \
    const u16* As_ = lds + ((sl) & 1) * 16384;                                                        \
    const u16* Bs_ = As_ + 8192;                                                                      \
    _Pragma("unroll")                                                                                 \
    for (int f = 0; f < 4; ++f) afX[f] = *(const bf16x8*)(As_ + arow[f] + (cso));                     \
    _Pragma("unroll")                                                                                 \
    for (int f = 0; f < 2; ++f) bqX[f] = *(const bf16x8*)(Bs_ + brow[f] + (cso));                     \
  } while (0)
#define MM(afX, bqX)                                                                                  \
  _Pragma("unroll") for (int nf = 0; nf < 2; ++nf)                                                    \
  _Pragma("unroll") for (int mf = 0; mf < 4; ++mf)                                                    \
    acc[mf][nf] = __builtin_amdgcn_mfma_f32_16x16x32_bf16(afX[mf], bqX[nf], acc[mf][nf], 0, 0, 0);

  bf16x8 afA[4], bqA[2], afB[4], bqB[2];

  STG(0);
  asm volatile("s_waitcnt vmcnt(0)" ::: "memory");
  __builtin_amdgcn_s_barrier();
  RD(afA, bqA, 0, cso0);
  asm volatile("s_waitcnt lgkmcnt(0)" ::: "memory");
  __builtin_amdgcn_sched_barrier(0);

  for (int s = 0; s < NS; ++s) {
    if (s + 1 < NS) STG(s + 1);
    RD(afB, bqB, s, cso1);
    __builtin_amdgcn_sched_barrier(0);
    __builtin_amdgcn_s_setprio(1);
    MM(afA, bqA);
    __builtin_amdgcn_s_setprio(0);
    asm volatile("s_waitcnt lgkmcnt(0)" ::: "memory");
    __builtin_amdgcn_sched_barrier(0);
    asm volatile("s_waitcnt vmcnt(0)" ::: "memory");
    __builtin_amdgcn_s_barrier();
    if (s + 1 < NS) RD(afA, bqA, s + 1, cso0);
    __builtin_amdgcn_sched_barrier(0);
    __builtin_amdgcn_s_setprio(1);
    MM(afB, bqB);
    __builtin_amdgcn_s_setprio(0);
    asm volatile("s_waitcnt lgkmcnt(0)" ::: "memory");
    __builtin_amdgcn_sched_barrier(0);
  }
#undef STG
#undef RD
#undef MM

  (void)Mr;
  if constexpr (EPI == 0) {
    const int obf = ODYN ? (flags[0] ? 0 : 1) : 0;
#pragma unroll
    for (int mf = 0; mf < 4; ++mf) {
#pragma unroll
      for (int nf = 0; nf < 2; ++nf) {
        const int col = tn + wc * 32 + nf * 16 + lr;
        const float bv = bias[col];
#pragma unroll
        for (int j = 0; j < 4; ++j) {
          const int rw = tm + wr * 64 + mf * 16 + lk * 4 + j;
          float vv = acc[mf][nf][j] + bv;
          if (RES) vv += res[(size_t)rw * N + col];
          if (GELU) vv = geluf(vv);
          if (WF) {
            if (ODYN && obf) ((u16*)outF)[(size_t)rw * N + col] = f2b(vv);
            else ((float*)outF)[(size_t)rw * N + col] = vv;
          }
          if (WB) outB[(size_t)rw * N + col] = f2b(vv);
        }
      }
    }
  } else {
    // ---- fused l2-norm epilogue (tile N=128 == one head slice) ----
    float* red = reinterpret_cast<float*>(lds);       // [128][4] f32 (2KB)
    u16* vt = lds + 4096;                             // [2][128][72] u16 (36KB)
    float bv2[2];
#pragma unroll
    for (int nf = 0; nf < 2; ++nf) bv2[nf] = bias[tn + wc * 32 + nf * 16 + lr];
    // per-row partial sum of squares (this wave's 32 cols)
    float ss[4][4];
#pragma unroll
    for (int mf = 0; mf < 4; ++mf)
#pragma unroll
      for (int j = 0; j < 4; ++j) {
        float s = 0.f;
#pragma unroll
        for (int nf = 0; nf < 2; ++nf) {
          float v = acc[mf][nf][j] + bv2[nf];
          s += v * v;
        }
        s += __shfl_xor(s, 1); s += __shfl_xor(s, 2); s += __shfl_xor(s, 4); s += __shfl_xor(s, 8);
        ss[mf][j] = s;
      }
    if (lr == 0) {
#pragma unroll
      for (int mf = 0; mf < 4; ++mf)
#pragma unroll
        for (int j = 0; j < 4; ++j) {
          const int row = wr * 64 + mf * 16 + lk * 4 + j;
          red[row * 4 + wc] = ss[mf][j];
        }
    }
    __syncthreads();
    float rs[4][4];
#pragma unroll
    for (int mf = 0; mf < 4; ++mf)
#pragma unroll
      for (int j = 0; j < 4; ++j) {
        const int row = wr * 64 + mf * 16 + lk * 4 + j;
        rs[mf][j] = rsqrtf(red[row * 4 + 0] + red[row * 4 + 1] + red[row * 4 + 2] + red[row * 4 + 3] + 1e-12f);
      }
    if constexpr (EPI == 1) {
      const int h = tn >> 7;
#pragma unroll
      for (int mf = 0; mf < 4; ++mf)
#pragma unroll
        for (int nf = 0; nf < 2; ++nf) {
          const int d = wc * 32 + nf * 16 + lr;
#pragma unroll
          for (int j = 0; j < 4; ++j) {
            const int rw = tm + wr * 64 + mf * 16 + lk * 4 + j;
            const int sR = rw >> 1, bb = rw & 1;
            float v = (acc[mf][nf][j] + bv2[nf]) * rs[mf][j];
            outB[(((size_t)(bb * NH_ + h) * S_) + sR) * D_ + d] = f2b(v);
          }
        }
    } else {
      const int h = tn >> 8;
      const int isV = (tn >> 7) & 1;
      if (!isV) {
#pragma unroll
        for (int mf = 0; mf < 4; ++mf)
#pragma unroll
          for (int nf = 0; nf < 2; ++nf) {
            const int d = wc * 32 + nf * 16 + lr;
#pragma unroll
            for (int j = 0; j < 4; ++j) {
              const int rw = tm + wr * 64 + mf * 16 + lk * 4 + j;
              const int mR = rw >> 1, bb = rw & 1;
              float v = (acc[mf][nf][j] + bv2[nf]) * rs[mf][j];
              outB[(((size_t)(bb * NH_ + h) * M_) + mR) * D_ + d] = f2b(v);
            }
          }
      } else {
        // V: scale -> LDS transpose (pad 72, 2-way banks) -> coalesced V^T write
#pragma unroll
        for (int mf = 0; mf < 4; ++mf)
#pragma unroll
          for (int nf = 0; nf < 2; ++nf) {
            const int d = wc * 32 + nf * 16 + lr;
#pragma unroll
            for (int j = 0; j < 4; ++j) {
              const int rl = wr * 64 + mf * 16 + lk * 4 + j;
              float v = (acc[mf][nf][j] + bv2[nf]) * rs[mf][j];
              vt[((rl & 1) * 128 + d) * 72 + (rl >> 1)] = f2b(v);
            }
          }
        __syncthreads();
        const int dd = t >> 2, bb = (t >> 1) & 1, half = t & 1;
        const u16* src = vt + ((size_t)(bb * 128 + dd) * 72) + half * 32;
        u16* dst = (u16*)outF + (((size_t)(bb * NH_ + h) * D_ + dd) * M_) + (tm >> 1) + half * 32;
#pragma unroll
        for (int i = 0; i < 4; ++i) *(bf16x8*)&dst[i * 8] = *(const bf16x8*)&src[i * 8];
      }
    }
  }
}

// -------------------------------------------------------------- attention
// unchanged (verified; ~130 us)
__global__ __launch_bounds__(256, 3) void attn_k(const u16* __restrict__ Q, const u16* __restrict__ Kq,
                                                 const u16* __restrict__ Vt, const u32* __restrict__ BM32,
                                                 u16* __restrict__ ctx) {
  __shared__ u16 Kl[2][4096];
  __shared__ u16 Vl[2][4096];
  __shared__ u16 Pl[4][16 * 40];
  const int t = threadIdx.x, w = t >> 6, l = t & 63, lr = l & 15, lk = l >> 4;
  const int lin = blockIdx.x;
  const int xcd = lin & 7, idx = lin >> 3;
  const int bh = xcd * 4 + (idx >> 5);
  const int chunk = idx & 31;
  const int b = bh >> 4, h = bh & 15;
  const int srow = chunk * 64 + w * 16;
  const u16* Qb = Q + ((size_t)bh * S_ + srow) * D_;
  bf16x8 qf[4];
#pragma unroll
  for (int kc = 0; kc < 4; ++kc)
    qf[kc] = *(const bf16x8*)&Qb[lr * D_ + kc * 32 + lk * 8];
  f32x4 oacc[8] = {};
  float den[4] = {};
  const u16* Kb = Kq + (size_t)bh * M_ * D_;
  const u16* Vb = Vt + (size_t)bh * D_ * M_;
  const float invn = 0.08838834764831845f;
  u32 ksrc[2], vsrc[2];
#pragma unroll
  for (int i = 0; i < 2; ++i) {
    const int kidx = i * 256 + t;
    const int kr = kidx >> 4, kc_ = (kidx & 15) ^ (kr & 7);
    ksrc[i] = (u32)kr * D_ + (u32)kc_ * 8;
    const int vidx = i * 256 + t;
    const int vd = vidx >> 2, vc = (vidx & 3) ^ ((vd >> 1) & 3);
    vsrc[i] = (u32)vd * M_ + (u32)vc * 8;
  }
  const int wdst = w * 64 * 8;
  u32 mrow[4];
#pragma unroll
  for (int j2 = 0; j2 < 4; ++j2)
    mrow[j2] = ((u32)b * S_ + (u32)(srow + lk * 4 + j2)) * 64u;

#define STG(buf, m0) do {                                                                              \
    _Pragma("unroll")                                                                                  \
    for (int i = 0; i < 2; ++i) {                                                                      \
      __builtin_amdgcn_global_load_lds(GLBP(Kb + (size_t)(m0) * D_ + ksrc[i]),                         \
                                       LDSP(&Kl[buf][i * 2048 + wdst]), 16, 0, 0);                     \
      __builtin_amdgcn_global_load_lds(GLBP(Vb + (size_t)(m0) + vsrc[i]),                              \
                                       LDSP(&Vl[buf][i * 2048 + wdst]), 16, 0, 0);                     \
    }                                                                                                  \
  } while (0)

  STG(0, 0);
  asm volatile("s_waitcnt vmcnt(0)" ::: "memory");
  __builtin_amdgcn_s_barrier();
  int cur = 0;

  for (int t64 = 0; t64 < M_ / 32; ++t64) {
    const int m0 = t64 * 32;
    if (t64 + 1 < M_ / 32) STG(cur ^ 1, m0 + 32);
    u32 mw[4];
#pragma unroll
    for (int j2 = 0; j2 < 4; ++j2) mw[j2] = BM32[mrow[j2] + t64];
    f32x4 sc[2] = {};
#pragma unroll
    for (int mf = 0; mf < 2; ++mf) {
      const int r = mf * 16 + lr;
#pragma unroll
      for (int kc = 0; kc < 4; ++kc) {
        const int cc = ((kc * 4 + lk) ^ (r & 7));
        bf16x8 kfv = *(const bf16x8*)&Kl[cur][r * 128 + cc * 8];
        sc[mf] = __builtin_amdgcn_mfma_f32_16x16x32_bf16(qf[kc], kfv, sc[mf], 0, 0, 0);
      }
    }
#pragma unroll
    for (int j2 = 0; j2 < 4; ++j2) {
      const int rloc = lk * 4 + j2;
#pragma unroll
      for (int mf = 0; mf < 2; ++mf) {
        float p = __expf(sc[mf][j2] * invn);
        p = ((mw[j2] >> (mf * 16 + lr)) & 1u) ? p : 0.0f;
        den[j2] += p;
        Pl[w][rloc * 40 + mf * 16 + lr] = f2b(p);
      }
    }
    asm volatile("s_waitcnt lgkmcnt(0)" ::: "memory");
    __builtin_amdgcn_sched_barrier(0);
    bf16x8 pa = *(const bf16x8*)&Pl[w][lr * 40 + lk * 8];
#pragma unroll
    for (int nf = 0; nf < 8; ++nf) {
      const int d = nf * 16 + lr;
      const int cc = lk ^ ((d >> 1) & 3);
      bf16x8 vfv = *(const bf16x8*)&Vl[cur][d * 32 + cc * 8];
      oacc[nf] = __builtin_amdgcn_mfma_f32_16x16x32_bf16(pa, vfv, oacc[nf], 0, 0, 0);
    }
    asm volatile("s_waitcnt vmcnt(0)" ::: "memory");
    __builtin_amdgcn_s_barrier();
    cur ^= 1;
  }
#undef STG
#pragma unroll
  for (int j2 = 0; j2 < 4; ++j2) {
    float d = den[j2];
    d += __shfl_xor(d, 1); d += __shfl_xor(d, 2); d += __shfl_xor(d, 4); d += __shfl_xor(d, 8);
    den[j2] = 1.0f / fmaxf(d, 1e-20f);
  }
#pragma unroll
  for (int nf = 0; nf < 8; ++nf)
#pragma unroll
    for (int j2 = 0; j2 < 4; ++j2) {
      const int s = srow + lk * 4 + j2;
      const int dd = nf * 16 + lr;
      ctx[((size_t)s * B_ + b) * H_ + h * D_ + dd] = f2b(oacc[nf][j2] * den[j2]);
    }
}

// ------------------------------------------------------------------- host
extern "C" void kernel_launch(void* const* d_in, const int* in_sizes, int n_in,
                              void* d_out, int out_size, void* d_ws, size_t ws_size,
                              hipStream_t stream) {
  (void)in_sizes; (void)n_in; (void)out_size; (void)ws_size;
  char* ws = (char*)d_ws;
  u16* WT     = (u16*)(ws + 0);
  void* MID   = (void*)(ws + 33554432);
  float* XF   = (float*)(ws + 100663296);
  u16* HB     = (u16*)(ws + 134217728);
  u16* MEMB   = (u16*)(ws + 150994944);
  u16* QB     = (u16*)(ws + 167772160);
  u16* KB     = (u16*)(ws + 184549376);
  u16* VTB    = (u16*)(ws + 201326592);
  u64* BMB    = (u64*)(ws + 218103808);
  float* SM   = (float*)(ws + 234881024);
  int* FLAGS  = (int*)(ws + 235044864);

  float* Bias1  = SM + 0;
  float* Bias1o = SM + 8192;
  float* BiasQ  = SM + 10240;
  float* BiasKV = SM + 12288;
  float* BiasD  = SM + 16384;
  float* Bias2  = SM + 18432;
  float* Bias2o = SM + 26624;
  float* G1v = SM + 28672; float* B1v = SM + 30720;
  float* G2v = SM + 32768; float* B2v = SM + 34816;
  float* G3v = SM + 36864; float* B3v = SM + 38912;

  detect_kinds<<<1, 64, 0, stream>>>((const u32*)d_in[0], (const u32*)d_in[2], FLAGS);

  cvt_all<<<160, 256, 0, stream>>>(d_in[10], d_in[12], d_in[14], d_in[16], d_in[18],
                                   d_in[20], d_in[22], d_in[3], d_in[4], d_in[5],
                                   d_in[6], d_in[7], d_in[8], FLAGS, SM);

  mask_bits<<<(B_ * S_ * M_) / 256, 256, 0, stream>>>(d_in[2], FLAGS, BMB);
  cast_in_bf16<<<(MB_ * H_ / 8) / 256, 256, 0, stream>>>(d_in[1], FLAGS, MEMB, MB_ * H_ / 8);

  dim3 blk(256);
  dim3 blk5(512);
  // ---- mlp1
  layernorm_k<1><<<SB_, blk, 0, stream>>>(d_in[0], FLAGS, G1v, B1v, HB);
  transpose_cast<<<dim3(FF_ / 64, H_ / 64), blk, 0, stream>>>(d_in[9], FLAGS, WT, H_, FF_);
  gemmra512<1, 0, 0, 1, 0, 0><<<dim3(FF_ / 128, SB_ / 128), blk5, 0, stream>>>(HB, WT, Bias1, nullptr, nullptr, (u16*)MID, FLAGS, SB_, FF_, H_);
  transpose_cast<<<dim3(H_ / 64, FF_ / 64), blk, 0, stream>>>(d_in[11], FLAGS, WT, FF_, H_);
  gemmra512<0, 0, 1, 0, 0, 0><<<dim3(H_ / 128, SB_ / 128), blk5, 0, stream>>>((u16*)MID, WT, Bias1o, nullptr, XF, nullptr, FLAGS, SB_, H_, FF_);

  // ---- memory attention
  layernorm_k<0><<<SB_, blk, 0, stream>>>(XF, FLAGS, G2v, B2v, HB);
  transpose_cast<<<dim3(H_ / 64, H_ / 64), blk, 0, stream>>>(d_in[13], FLAGS, WT, H_, H_);
  gemmra512<0, 0, 0, 0, 0, 1><<<dim3(H_ / 128, SB_ / 128), blk5, 0, stream>>>(HB, WT, BiasQ, nullptr, nullptr, QB, FLAGS, SB_, H_, H_);
  transpose_cast<<<dim3(2 * H_ / 64, H_ / 64), blk, 0, stream>>>(d_in[15], FLAGS, WT, H_, 2 * H_);
  gemmra512<0, 0, 0, 0, 0, 2><<<dim3(2 * H_ / 128, MB_ / 128), blk5, 0, stream>>>(MEMB, WT, BiasKV, nullptr, VTB, KB, FLAGS, MB_, 2 * H_, H_);
  attn_k<<<1024, blk, 0, stream>>>(QB, KB, VTB, (const u32*)BMB, MEMB);
  transpose_cast<<<dim3(H_ / 64, H_ / 64), blk, 0, stream>>>(d_in[17], FLAGS, WT, H_, H_);
  gemmra512<0, 1, 1, 0, 0, 0><<<dim3(H_ / 128, SB_ / 128), blk5, 0, stream>>>(MEMB, WT, BiasD, XF, XF, nullptr, FLAGS, SB_, H_, H_);

  // ---- mlp2
  layernorm_k<0><<<SB_, blk, 0, stream>>>(XF, FLAGS, G3v, B3v, HB);
  transpose_cast<<<dim3(FF_ / 64, H_ / 64), blk, 0, stream>>>(d_in[19], FLAGS, WT, H_, FF_);
  gemmra512<1, 0, 0, 1, 0, 0><<<dim3(FF_ / 128, SB_ / 128), blk5, 0, stream>>>(HB, WT, Bias2, nullptr, nullptr, (u16*)MID, FLAGS, SB_, FF_, H_);
  transpose_cast<<<dim3(H_ / 64, FF_ / 64), blk, 0, stream>>>(d_in[21], FLAGS, WT, FF_, H_);
  gemmra512<0, 1, 1, 0, 1, 0><<<dim3(H_ / 128, SB_ / 128), blk5, 0, stream>>>((u16*)MID, WT, Bias2o, XF, d_out, nullptr, FLAGS, SB_, H_, FF_);
}